// Round 13
// baseline (280.892 us; speedup 1.0000x reference)
//
#include <hip/hip_runtime.h>
#include <hip/hip_bf16.h>
#include <hip/hip_fp16.h>
#include <math.h>

#define NN 100000
#define EE 1600000
#define MM 20000
#define EPB 768                         // edges per partition block (multiple of 256)
#define NBLK ((EE + EPB - 1) / EPB)     // 2084 partition blocks
#define NBC 250                         // coarse dst buckets
#define BWC 400                         // nodes per bucket (250*400 = 100000 exactly)
#define N_SCAN (NBC * NBLK + 1)         // 521001 (+ sentinel)
#define SMASK 0x1FFFF                   // low 17 bits: src id

// ---- tiny: v1[16] = We1 @ a_e1 (64), v2[16] = We2 @ a_e2 (32) ----
__global__ void k_v(const float* __restrict__ We1, const float* __restrict__ ae1v,
                    const float* __restrict__ We2, const float* __restrict__ ae2v,
                    float* __restrict__ v1, float* __restrict__ v2) {
    int t = threadIdx.x;
    if (t < 16) {
        float s = 0.f;
        for (int c = 0; c < 64; ++c) s += We1[t * 64 + c] * ae1v[c];
        v1[t] = s;
    } else if (t < 32) {
        int r = t - 16;
        float s = 0.f;
        for (int c = 0; c < 32; ++c) s += We2[r * 32 + c] * ae2v[c];
        v2[r] = s;
    }
}

// ---- layer-1 node transform: W in registers, x broadcast via shuffle ----
__global__ __launch_bounds__(256) void k_node1(
    const float* __restrict__ x, const float* __restrict__ W,
    const float* __restrict__ a_s, const float* __restrict__ a_d,
    __half* __restrict__ hx, float* __restrict__ aS, float* __restrict__ aD,
    int n_nodes)
{
    int lane = threadIdx.x & 63;
    int wid = (blockIdx.x * 256 + threadIdx.x) >> 6;
    int nwaves = gridDim.x * 4;
    float wreg[64];
#pragma unroll
    for (int k = 0; k < 64; ++k) wreg[k] = W[k * 64 + lane];
    float as = a_s[lane], ad = a_d[lane];
    for (int n = wid; n < n_nodes; n += nwaves) {
        float xr = x[(size_t)n * 64 + lane];
        float h = 0.f;
#pragma unroll
        for (int k = 0; k < 64; ++k) h += __shfl(xr, k) * wreg[k];
        hx[(size_t)n * 64 + lane] = __float2half(h);
        float ps = h * as, pd = h * ad;
#pragma unroll
        for (int o = 32; o > 0; o >>= 1) { ps += __shfl_xor(ps, o); pd += __shfl_xor(pd, o); }
        if (lane == 0) { aS[n] = ps; aD[n] = pd; }
    }
}

// ---- fused: edge dots (both layers, fp16-packed) + per-(bucket,block) histogram ----
__global__ __launch_bounds__(256) void k_aebh(
    const float* __restrict__ ea, const float* __restrict__ v1, const float* __restrict__ v2,
    const int* __restrict__ dst, unsigned* __restrict__ ae12,
    int* __restrict__ bh, int E)
{
    __shared__ int hl[NBC];
    int tid = threadIdx.x, blk = blockIdx.x;
    for (int j = tid; j < NBC; j += 256) hl[j] = 0;
    __syncthreads();
    const float4* v14 = (const float4*)v1;
    const float4* v24 = (const float4*)v2;
    float4 va0 = v14[0], va1 = v14[1], va2 = v14[2], va3 = v14[3];
    float4 vb0 = v24[0], vb1 = v24[1], vb2 = v24[2], vb3 = v24[3];
    int e0 = blk * EPB, e1 = min(E, e0 + EPB);
    for (int e = e0 + tid; e < e1; e += 256) {
        const float4* p4 = (const float4*)(ea + (size_t)e * 16);
        float4 q0 = p4[0], q1 = p4[1], q2 = p4[2], q3 = p4[3];
        float s1 = q0.x * va0.x + q0.y * va0.y + q0.z * va0.z + q0.w * va0.w
                 + q1.x * va1.x + q1.y * va1.y + q1.z * va1.z + q1.w * va1.w
                 + q2.x * va2.x + q2.y * va2.y + q2.z * va2.z + q2.w * va2.w
                 + q3.x * va3.x + q3.y * va3.y + q3.z * va3.z + q3.w * va3.w;
        float s2 = q0.x * vb0.x + q0.y * vb0.y + q0.z * vb0.z + q0.w * vb0.w
                 + q1.x * vb1.x + q1.y * vb1.y + q1.z * vb1.z + q1.w * vb1.w
                 + q2.x * vb2.x + q2.y * vb2.y + q2.z * vb2.z + q2.w * vb2.w
                 + q3.x * vb3.x + q3.y * vb3.y + q3.z * vb3.z + q3.w * vb3.w;
        ae12[e] = (unsigned)__half_as_ushort(__float2half(s1))
                | ((unsigned)__half_as_ushort(__float2half(s2)) << 16);
        atomicAdd(&hl[dst[e] / BWC], 1);
    }
    __syncthreads();
    for (int j = tid; j < NBC; j += 256) bh[j * NBLK + blk] = hl[j];
    if (blk == 0 && tid == 0) bh[NBC * NBLK] = 0;   // sentinel -> scan total == E
}

// ---- scan kernels: exclusive prefix (2048 elems/block) ----
__global__ __launch_bounds__(256) void k_scan1(const int* __restrict__ deg, int* __restrict__ pre,
                                               int* __restrict__ bsum, int n) {
    __shared__ int wsum[4];
    int t = threadIdx.x;
    int base = blockIdx.x * 2048 + t * 8;
    int v[8]; int s = 0;
#pragma unroll
    for (int i = 0; i < 8; ++i) { int idx = base + i; int d = (idx < n) ? deg[idx] : 0; v[i] = s; s += d; }
    int lane = t & 63, wv = t >> 6;
    int incl = s;
#pragma unroll
    for (int off = 1; off < 64; off <<= 1) { int y = __shfl_up(incl, off); if (lane >= off) incl += y; }
    if (lane == 63) wsum[wv] = incl;
    __syncthreads();
    int woff = 0;
    for (int w = 0; w < wv; ++w) woff += wsum[w];
    int texcl = woff + incl - s;
#pragma unroll
    for (int i = 0; i < 8; ++i) { int idx = base + i; if (idx < n) pre[idx] = texcl + v[i]; }
    if (t == 255) bsum[blockIdx.x] = woff + incl;
}

__global__ __launch_bounds__(256) void k_scan2(int* __restrict__ bsum, int nb) {
    __shared__ int ws[4];
    int t = threadIdx.x, lane = t & 63, wv = t >> 6;
    int x = (t < nb) ? bsum[t] : 0;
    int incl = x;
#pragma unroll
    for (int off = 1; off < 64; off <<= 1) { int y = __shfl_up(incl, off); if (lane >= off) incl += y; }
    if (lane == 63) ws[wv] = incl;
    __syncthreads();
    int woff = 0;
    for (int w = 0; w < wv; ++w) woff += ws[w];
    if (t < nb) bsum[t] = woff + incl - x;
}

__global__ void k_scan3b(int* __restrict__ pre, const int* __restrict__ bsum, int n) {
    int i = blockIdx.x * 256 + threadIdx.x;
    if (i < n) pre[i] += bsum[i >> 11];
}

// ---- pass 1: pure bookkeeping scatter into 250 coarse dst buckets,
//      block-owned segments, positions from LDS cursors (no global atomics) ----
__global__ __launch_bounds__(256) void k_part(
    const int* __restrict__ src, const int* __restrict__ dst,
    const unsigned* __restrict__ ae12,
    const int* __restrict__ scanned, uint2* __restrict__ recMid, int E)
{
    __shared__ int lcur[NBC];
    int tid = threadIdx.x, blk = blockIdx.x;
    for (int j = tid; j < NBC; j += 256) lcur[j] = scanned[j * NBLK + blk];
    __syncthreads();
    int e0 = blk * EPB, e1 = min(E, e0 + EPB);
    for (int e = e0 + tid; e < e1; e += 256) {
        int s = src[e], d = dst[e];
        unsigned w = ae12[e];
        int b = d / BWC;
        int dloc = d - b * BWC;                       // < 400, 9 bits
        unsigned lo = (unsigned)s | ((unsigned)dloc << 17);
        int pos = atomicAdd(&lcur[b], 1);
        recMid[pos] = make_uint2(lo, w);
    }
}

// ---- pass 2: one block per bucket: LDS hist -> LDS scan -> rowptr -> place ----
__global__ __launch_bounds__(256) void k_build(
    const int* __restrict__ scanned, const uint2* __restrict__ recMid,
    int* __restrict__ rowptr, uint2* __restrict__ rec, int E)
{
    __shared__ int hist[BWC];
    __shared__ int lofs[BWC];
    __shared__ int wsum[4];
    int tid = threadIdx.x, b = blockIdx.x;
    int B0 = scanned[b * NBLK];
    int B1 = scanned[(b + 1) * NBLK];                 // b==NBC-1 hits sentinel == E
    for (int j = tid; j < BWC; j += 256) hist[j] = 0;
    __syncthreads();
    for (int i = B0 + tid; i < B1; i += 256) atomicAdd(&hist[recMid[i].x >> 17], 1);
    __syncthreads();
    // exclusive scan over hist[0..BWC) -> lofs (2 consecutive elems per thread)
    int lane = tid & 63, wv = tid >> 6;
    int i0 = 2 * tid, i1 = 2 * tid + 1;
    int a0 = (i0 < BWC) ? hist[i0] : 0;
    int a1 = (i1 < BWC) ? hist[i1] : 0;
    int s = a0 + a1;
    int incl = s;
#pragma unroll
    for (int off = 1; off < 64; off <<= 1) { int y = __shfl_up(incl, off); if (lane >= off) incl += y; }
    if (lane == 63) wsum[wv] = incl;
    __syncthreads();
    int woff = 0;
    for (int w = 0; w < wv; ++w) woff += wsum[w];
    int base = woff + incl - s;
    if (i0 < BWC) lofs[i0] = base;
    if (i1 < BWC) lofs[i1] = base + a0;
    __syncthreads();
    // rowptr for this bucket (coalesced)
    for (int j = tid; j < BWC; j += 256) rowptr[b * BWC + j] = B0 + lofs[j];
    if (b == NBC - 1 && tid == 0) rowptr[NN] = E;
    __syncthreads();
    // place records at exact CSR slots via LDS cursors
    for (int i = B0 + tid; i < B1; i += 256) {
        uint2 r = recMid[i];
        int nl = (int)(r.x >> 17);
        int p = atomicAdd(&lofs[nl], 1);
        rec[B0 + p] = r;
    }
}

// ---- layer-1 pull aggregation (alpha finished here) + finalize -> h1 ----
__global__ __launch_bounds__(256) void k_agg1(
    const int* __restrict__ rowptr,
    const uint2* __restrict__ rec, const __half* __restrict__ hx,
    const float* __restrict__ aS, const float* __restrict__ aD,
    const float* __restrict__ b, float* __restrict__ h1, int n_nodes)
{
    int wv = threadIdx.x >> 6, lane = threadIdx.x & 63;
    int n = blockIdx.x * 4 + wv;
    if (n >= n_nodes) return;
    int start = rowptr[n], end = rowptr[n + 1];
    float aDn = aD[n];
    float r = 0.f, den = 0.f;
    for (int base = start; base < end; base += 64) {
        int cnt = min(end - base, 64);
        int s = 0; float ex = 0.f;
        if (lane < cnt) {
            uint2 R = rec[base + lane];
            s = (int)(R.x & SMASK);
            float s1 = __half2float(__ushort_as_half((unsigned short)(R.y & 0xFFFFu)));
            float a = aS[s] + aDn + s1;
            a = a > 0.f ? a : 0.2f * a;
            ex = __expf(a);
        }
        int j = 0;
        for (; j + 4 <= cnt; j += 4) {
            int s0 = __shfl(s, j), s1i = __shfl(s, j + 1), s2 = __shfl(s, j + 2), s3 = __shfl(s, j + 3);
            float e0 = __shfl(ex, j), e1 = __shfl(ex, j + 1), e2 = __shfl(ex, j + 2), e3 = __shfl(ex, j + 3);
            float h0 = __half2float(hx[(size_t)s0 * 64 + lane]);
            float h1v = __half2float(hx[(size_t)s1i * 64 + lane]);
            float h2 = __half2float(hx[(size_t)s2 * 64 + lane]);
            float h3 = __half2float(hx[(size_t)s3 * 64 + lane]);
            r += e0 * h0; r += e1 * h1v; r += e2 * h2; r += e3 * h3;
            den += e0 + e1 + e2 + e3;
        }
        for (; j < cnt; ++j) {
            int sj = __shfl(s, j); float ej = __shfl(ex, j);
            r += ej * __half2float(hx[(size_t)sj * 64 + lane]);
            den += ej;
        }
    }
    float al = aS[n] + aDn;
    al = al > 0.f ? al : 0.2f * al;
    float exl = __expf(al);
    float hself = __half2float(hx[(size_t)n * 64 + lane]);
    float val = (r + exl * hself) / (den + exl) + b[lane];
    h1[(size_t)n * 64 + lane] = val > 0.f ? val : expm1f(val);
}

// ---- layer-2 node transform: W in registers, h1 broadcast via shuffle ----
__global__ __launch_bounds__(256) void k_node2(
    const float* __restrict__ h1, const float* __restrict__ W,
    const float* __restrict__ a_s, const float* __restrict__ a_d,
    float* __restrict__ hx, float* __restrict__ aS, float* __restrict__ aD, int n_nodes)
{
    int lane = threadIdx.x & 63;
    int half = lane >> 5, c = lane & 31;
    int wid = (blockIdx.x * 256 + threadIdx.x) >> 6;
    int nwaves = gridDim.x * 4;
    float wreg[64];
#pragma unroll
    for (int k = 0; k < 64; ++k) wreg[k] = W[k * 32 + c];
    float as = a_s[c], ad = a_d[c];
    int npairs = (n_nodes + 1) >> 1;
    for (int p = wid; p < npairs; p += nwaves) {
        int n = p * 2 + half;             // lanes 0-31: node 2p; lanes 32-63: node 2p+1
        bool act = (n < n_nodes);
        float xr0 = 0.f, xr1 = 0.f;
        if (act) {
            xr0 = h1[(size_t)n * 64 + c];
            xr1 = h1[(size_t)n * 64 + 32 + c];
        }
        float h = 0.f;
        int base = half << 5;             // broadcast from own half
#pragma unroll
        for (int k = 0; k < 32; ++k) {
            h += __shfl(xr0, base + k) * wreg[k];
            h += __shfl(xr1, base + k) * wreg[32 + k];
        }
        if (act) {
            hx[(size_t)n * 32 + c] = h;
            float ps = h * as, pd = h * ad;
#pragma unroll
            for (int o = 16; o > 0; o >>= 1) { ps += __shfl_xor(ps, o, 32); pd += __shfl_xor(pd, o, 32); }
            if (c == 0) { aS[n] = ps; aD[n] = pd; }
        }
    }
}

// ---- layer-2 pull aggregation over masked nodes only + finalize -> out ----
__global__ __launch_bounds__(256) void k_agg2(
    const int* __restrict__ mask, const int* __restrict__ rowptr,
    const uint2* __restrict__ rec, const float* __restrict__ hx,
    const float* __restrict__ aS, const float* __restrict__ aD,
    const float* __restrict__ b, float* __restrict__ out, int m_cnt)
{
    int wv = threadIdx.x >> 6, lane = threadIdx.x & 63;
    int m = blockIdx.x * 4 + wv;
    if (m >= m_cnt) return;
    int n = mask[m];
    int start = rowptr[n], end = rowptr[n + 1];
    float aDn = aD[n];
    int half = lane >> 5, c = lane & 31;
    float r = 0.f, den = 0.f;
    for (int base = start; base < end; base += 64) {
        int cnt = min(end - base, 64);
        int s = 0; float ex = 0.f;
        if (lane < cnt) {
            uint2 R = rec[base + lane];
            s = (int)(R.x & SMASK);
            float ae2 = __half2float(__ushort_as_half((unsigned short)(R.y >> 16)));
            float a = aS[s] + aDn + ae2;
            a = a > 0.f ? a : 0.2f * a;
            ex = __expf(a);
        }
        int j = 0;
        for (; j + 8 <= cnt; j += 8) {
            int j0 = j + half, j2 = j + 2 + half, j4 = j + 4 + half, j6 = j + 6 + half;
            int s0 = __shfl(s, j0), s2v = __shfl(s, j2), s4 = __shfl(s, j4), s6 = __shfl(s, j6);
            float e0 = __shfl(ex, j0), e2 = __shfl(ex, j2), e4 = __shfl(ex, j4), e6 = __shfl(ex, j6);
            r += e0 * hx[(size_t)s0 * 32 + c];
            r += e2 * hx[(size_t)s2v * 32 + c];
            r += e4 * hx[(size_t)s4 * 32 + c];
            r += e6 * hx[(size_t)s6 * 32 + c];
            den += e0 + e2 + e4 + e6;
        }
        for (; j < cnt; j += 2) {
            int jj = j + half;
            if (jj < cnt) {
                int sj = __shfl(s, jj); float ej = __shfl(ex, jj);
                r += ej * hx[(size_t)sj * 32 + c];
                den += ej;
            }
        }
    }
    float ro = __shfl(r, lane ^ 32);
    float do_ = __shfl(den, lane ^ 32);
    r += ro; den += do_;
    if (half == 0) {
        float al = aS[n] + aDn;
        al = al > 0.f ? al : 0.2f * al;
        float exl = __expf(al);
        float val = (r + exl * hx[(size_t)n * 32 + c]) / (den + exl) + b[c];
        out[(size_t)m * 32 + c] = val > 0.f ? val : expm1f(val);
    }
}

extern "C" void kernel_launch(void* const* d_in, const int* in_sizes, int n_in,
                              void* d_out, int out_size, void* d_ws, size_t ws_size,
                              hipStream_t stream) {
    const float* x    = (const float*)d_in[0];
    const int*   ei   = (const int*)d_in[1];
    const int*   mask = (const int*)d_in[2];
    const float* ea   = (const float*)d_in[3];
    const float* W1   = (const float*)d_in[4];
    const float* a_s1 = (const float*)d_in[5];
    const float* a_d1 = (const float*)d_in[6];
    const float* We1  = (const float*)d_in[7];
    const float* a_e1 = (const float*)d_in[8];
    const float* b1   = (const float*)d_in[9];
    const float* W2   = (const float*)d_in[10];
    const float* a_s2 = (const float*)d_in[11];
    const float* a_d2 = (const float*)d_in[12];
    const float* We2  = (const float*)d_in[13];
    const float* a_e2 = (const float*)d_in[14];
    const float* b2   = (const float*)d_in[15];
    const int* src = ei;
    const int* dst = ei + EE;
    float* out = (float*)d_out;

    char* w = (char*)d_ws;
    size_t off = 0;
    auto take = [&](size_t bytes) -> char* {
        char* p = w + off;
        off += (bytes + 255) & ~(size_t)255;
        return p;
    };
    float*    v1      = (float*)take(16 * 4);
    float*    v2      = (float*)take(16 * 4);
    __half*   hx1h    = (__half*)take((size_t)NN * 64 * 2);
    float*    aS1     = (float*)take((size_t)NN * 4);
    float*    aD1     = (float*)take((size_t)NN * 4);
    float*    h1      = (float*)take((size_t)NN * 64 * 4);
    float*    hx2     = (float*)take((size_t)NN * 32 * 4);
    float*    aS2     = (float*)take((size_t)NN * 4);
    float*    aD2     = (float*)take((size_t)NN * 4);
    int*      rowptr  = (int*)take(((size_t)NN + 1) * 4);
    unsigned* ae12    = (unsigned*)take((size_t)EE * 4);
    int*      bh      = (int*)take((size_t)N_SCAN * 4);
    int*      scanned = (int*)take((size_t)N_SCAN * 4);
    int*      bsum    = (int*)take(256 * 4);
    uint2*    recMid  = (uint2*)take((size_t)EE * 8);
    uint2*    rec     = (uint2*)take((size_t)EE * 8);

    const int nb_bh = (N_SCAN + 2047) / 2048;     // 255 (<= 256)

    k_v<<<1, 64, 0, stream>>>(We1, a_e1, We2, a_e2, v1, v2);
    k_node1<<<1024, 256, 0, stream>>>(x, W1, a_s1, a_d1, hx1h, aS1, aD1, NN);
    k_aebh<<<NBLK, 256, 0, stream>>>(ea, v1, v2, dst, ae12, bh, EE);
    k_scan1<<<nb_bh, 256, 0, stream>>>(bh, scanned, bsum, N_SCAN);
    k_scan2<<<1, 256, 0, stream>>>(bsum, nb_bh);
    k_scan3b<<<(N_SCAN + 255) / 256, 256, 0, stream>>>(scanned, bsum, N_SCAN);
    k_part<<<NBLK, 256, 0, stream>>>(src, dst, ae12, scanned, recMid, EE);
    k_build<<<NBC, 256, 0, stream>>>(scanned, recMid, rowptr, rec, EE);
    k_agg1<<<(NN + 3) / 4, 256, 0, stream>>>(rowptr, rec, hx1h, aS1, aD1, b1, h1, NN);
    k_node2<<<1024, 256, 0, stream>>>(h1, W2, a_s2, a_d2, hx2, aS2, aD2, NN);
    k_agg2<<<(MM + 3) / 4, 256, 0, stream>>>(mask, rowptr, rec, hx2, aS2, aD2, b2, out, MM);
}

// Round 14
// 210.464 us; speedup vs baseline: 1.3346x; 1.3346x over previous
//
#include <hip/hip_runtime.h>
#include <hip/hip_bf16.h>
#include <hip/hip_fp16.h>
#include <math.h>

#define NN 100000
#define EE 1600000
#define MM 20000
#define EPB 768                         // edges per partition block (multiple of 256)
#define NBLK ((EE + EPB - 1) / EPB)     // 2084 partition blocks
#define NBC 250                         // coarse dst buckets
#define BWC 400                         // nodes per bucket (250*400 = 100000 exactly)
#define N_SCAN (NBC * NBLK + 1)         // 521001 (+ sentinel)
#define SMASK 0x1FFFF                   // low 17 bits: src id

// ---- tiny: v1[16] = We1 @ a_e1 (64), v2[16] = We2 @ a_e2 (32) ----
__global__ void k_v(const float* __restrict__ We1, const float* __restrict__ ae1v,
                    const float* __restrict__ We2, const float* __restrict__ ae2v,
                    float* __restrict__ v1, float* __restrict__ v2) {
    int t = threadIdx.x;
    if (t < 16) {
        float s = 0.f;
        for (int c = 0; c < 64; ++c) s += We1[t * 64 + c] * ae1v[c];
        v1[t] = s;
    } else if (t < 32) {
        int r = t - 16;
        float s = 0.f;
        for (int c = 0; c < 32; ++c) s += We2[r * 32 + c] * ae2v[c];
        v2[r] = s;
    }
}

// ---- layer-1 node transform: W in regs, x via broadcast-b128 LDS reads ----
__global__ __launch_bounds__(256) void k_node1(
    const float* __restrict__ x, const float* __restrict__ W,
    const float* __restrict__ a_s, const float* __restrict__ a_d,
    __half* __restrict__ hx, float* __restrict__ aS, float* __restrict__ aD,
    int n_nodes)
{
    __shared__ float xs[16][64];
    int tid = threadIdx.x;
    int lane = tid & 63, wv = tid >> 6;
    float wreg[64];
#pragma unroll
    for (int k = 0; k < 64; ++k) wreg[k] = W[k * 64 + lane];
    float as = a_s[lane], ad = a_d[lane];
    for (int n0 = blockIdx.x * 16; n0 < n_nodes; n0 += gridDim.x * 16) {
        __syncthreads();
        for (int i = tid; i < 16 * 64; i += 256) {
            int nn = n0 + (i >> 6);
            xs[i >> 6][i & 63] = (nn < n_nodes) ? x[(size_t)nn * 64 + (i & 63)] : 0.f;
        }
        __syncthreads();
#pragma unroll
        for (int r = 0; r < 4; ++r) {
            int n = n0 + wv * 4 + r;
            if (n >= n_nodes) break;
            const float4* xp = (const float4*)xs[wv * 4 + r];
            float h = 0.f;
#pragma unroll
            for (int k4 = 0; k4 < 16; ++k4) {
                float4 xv = xp[k4];      // broadcast read: all lanes same address
                h += xv.x * wreg[4 * k4] + xv.y * wreg[4 * k4 + 1]
                   + xv.z * wreg[4 * k4 + 2] + xv.w * wreg[4 * k4 + 3];
            }
            hx[(size_t)n * 64 + lane] = __float2half(h);
            float ps = h * as, pd = h * ad;
#pragma unroll
            for (int o = 32; o > 0; o >>= 1) { ps += __shfl_xor(ps, o); pd += __shfl_xor(pd, o); }
            if (lane == 0) { aS[n] = ps; aD[n] = pd; }
        }
    }
}

// ---- fused: edge dots (both layers, fp16-packed) + per-(bucket,block) histogram ----
__global__ __launch_bounds__(256) void k_aebh(
    const float* __restrict__ ea, const float* __restrict__ v1, const float* __restrict__ v2,
    const int* __restrict__ dst, unsigned* __restrict__ ae12,
    int* __restrict__ bh, int E)
{
    __shared__ int hl[NBC];
    int tid = threadIdx.x, blk = blockIdx.x;
    for (int j = tid; j < NBC; j += 256) hl[j] = 0;
    __syncthreads();
    const float4* v14 = (const float4*)v1;
    const float4* v24 = (const float4*)v2;
    float4 va0 = v14[0], va1 = v14[1], va2 = v14[2], va3 = v14[3];
    float4 vb0 = v24[0], vb1 = v24[1], vb2 = v24[2], vb3 = v24[3];
    int e0 = blk * EPB, e1 = min(E, e0 + EPB);
    for (int e = e0 + tid; e < e1; e += 256) {
        const float4* p4 = (const float4*)(ea + (size_t)e * 16);
        float4 q0 = p4[0], q1 = p4[1], q2 = p4[2], q3 = p4[3];
        float s1 = q0.x * va0.x + q0.y * va0.y + q0.z * va0.z + q0.w * va0.w
                 + q1.x * va1.x + q1.y * va1.y + q1.z * va1.z + q1.w * va1.w
                 + q2.x * va2.x + q2.y * va2.y + q2.z * va2.z + q2.w * va2.w
                 + q3.x * va3.x + q3.y * va3.y + q3.z * va3.z + q3.w * va3.w;
        float s2 = q0.x * vb0.x + q0.y * vb0.y + q0.z * vb0.z + q0.w * vb0.w
                 + q1.x * vb1.x + q1.y * vb1.y + q1.z * vb1.z + q1.w * vb1.w
                 + q2.x * vb2.x + q2.y * vb2.y + q2.z * vb2.z + q2.w * vb2.w
                 + q3.x * vb3.x + q3.y * vb3.y + q3.z * vb3.z + q3.w * vb3.w;
        ae12[e] = (unsigned)__half_as_ushort(__float2half(s1))
                | ((unsigned)__half_as_ushort(__float2half(s2)) << 16);
        atomicAdd(&hl[dst[e] / BWC], 1);
    }
    __syncthreads();
    for (int j = tid; j < NBC; j += 256) bh[j * NBLK + blk] = hl[j];
    if (blk == 0 && tid == 0) bh[NBC * NBLK] = 0;   // sentinel -> scan total == E
}

// ---- scan kernels: exclusive prefix (2048 elems/block) ----
__global__ __launch_bounds__(256) void k_scan1(const int* __restrict__ deg, int* __restrict__ pre,
                                               int* __restrict__ bsum, int n) {
    __shared__ int wsum[4];
    int t = threadIdx.x;
    int base = blockIdx.x * 2048 + t * 8;
    int v[8]; int s = 0;
#pragma unroll
    for (int i = 0; i < 8; ++i) { int idx = base + i; int d = (idx < n) ? deg[idx] : 0; v[i] = s; s += d; }
    int lane = t & 63, wv = t >> 6;
    int incl = s;
#pragma unroll
    for (int off = 1; off < 64; off <<= 1) { int y = __shfl_up(incl, off); if (lane >= off) incl += y; }
    if (lane == 63) wsum[wv] = incl;
    __syncthreads();
    int woff = 0;
    for (int w = 0; w < wv; ++w) woff += wsum[w];
    int texcl = woff + incl - s;
#pragma unroll
    for (int i = 0; i < 8; ++i) { int idx = base + i; if (idx < n) pre[idx] = texcl + v[i]; }
    if (t == 255) bsum[blockIdx.x] = woff + incl;
}

__global__ __launch_bounds__(256) void k_scan2(int* __restrict__ bsum, int nb) {
    __shared__ int ws[4];
    int t = threadIdx.x, lane = t & 63, wv = t >> 6;
    int x = (t < nb) ? bsum[t] : 0;
    int incl = x;
#pragma unroll
    for (int off = 1; off < 64; off <<= 1) { int y = __shfl_up(incl, off); if (lane >= off) incl += y; }
    if (lane == 63) ws[wv] = incl;
    __syncthreads();
    int woff = 0;
    for (int w = 0; w < wv; ++w) woff += ws[w];
    if (t < nb) bsum[t] = woff + incl - x;
}

__global__ void k_scan3b(int* __restrict__ pre, const int* __restrict__ bsum, int n) {
    int i = blockIdx.x * 256 + threadIdx.x;
    if (i < n) pre[i] += bsum[i >> 11];
}

// ---- pass 1: pure bookkeeping scatter into 250 coarse dst buckets,
//      block-owned segments, positions from LDS cursors (no global atomics) ----
__global__ __launch_bounds__(256) void k_part(
    const int* __restrict__ src, const int* __restrict__ dst,
    const unsigned* __restrict__ ae12,
    const int* __restrict__ scanned, uint2* __restrict__ recMid, int E)
{
    __shared__ int lcur[NBC];
    int tid = threadIdx.x, blk = blockIdx.x;
    for (int j = tid; j < NBC; j += 256) lcur[j] = scanned[j * NBLK + blk];
    __syncthreads();
    int e0 = blk * EPB, e1 = min(E, e0 + EPB);
    for (int e = e0 + tid; e < e1; e += 256) {
        int s = src[e], d = dst[e];
        unsigned w = ae12[e];
        int b = d / BWC;
        int dloc = d - b * BWC;                       // < 400, 9 bits
        unsigned lo = (unsigned)s | ((unsigned)dloc << 17);
        int pos = atomicAdd(&lcur[b], 1);
        recMid[pos] = make_uint2(lo, w);
    }
}

// ---- pass 2: one block per bucket: LDS hist -> LDS scan -> rowptr -> place ----
__global__ __launch_bounds__(256) void k_build(
    const int* __restrict__ scanned, const uint2* __restrict__ recMid,
    int* __restrict__ rowptr, uint2* __restrict__ rec, int E)
{
    __shared__ int hist[BWC];
    __shared__ int lofs[BWC];
    __shared__ int wsum[4];
    int tid = threadIdx.x, b = blockIdx.x;
    int B0 = scanned[b * NBLK];
    int B1 = scanned[(b + 1) * NBLK];                 // b==NBC-1 hits sentinel == E
    for (int j = tid; j < BWC; j += 256) hist[j] = 0;
    __syncthreads();
    for (int i = B0 + tid; i < B1; i += 256) atomicAdd(&hist[recMid[i].x >> 17], 1);
    __syncthreads();
    // exclusive scan over hist[0..BWC) -> lofs (2 consecutive elems per thread)
    int lane = tid & 63, wv = tid >> 6;
    int i0 = 2 * tid, i1 = 2 * tid + 1;
    int a0 = (i0 < BWC) ? hist[i0] : 0;
    int a1 = (i1 < BWC) ? hist[i1] : 0;
    int s = a0 + a1;
    int incl = s;
#pragma unroll
    for (int off = 1; off < 64; off <<= 1) { int y = __shfl_up(incl, off); if (lane >= off) incl += y; }
    if (lane == 63) wsum[wv] = incl;
    __syncthreads();
    int woff = 0;
    for (int w = 0; w < wv; ++w) woff += wsum[w];
    int base = woff + incl - s;
    if (i0 < BWC) lofs[i0] = base;
    if (i1 < BWC) lofs[i1] = base + a0;
    __syncthreads();
    // rowptr for this bucket (coalesced)
    for (int j = tid; j < BWC; j += 256) rowptr[b * BWC + j] = B0 + lofs[j];
    if (b == NBC - 1 && tid == 0) rowptr[NN] = E;
    __syncthreads();
    // place records at exact CSR slots via LDS cursors
    for (int i = B0 + tid; i < B1; i += 256) {
        uint2 r = recMid[i];
        int nl = (int)(r.x >> 17);
        int p = atomicAdd(&lofs[nl], 1);
        rec[B0 + p] = r;
    }
}

// ---- layer-1 pull aggregation (alpha finished here) + finalize -> h1 ----
__global__ __launch_bounds__(256) void k_agg1(
    const int* __restrict__ rowptr,
    const uint2* __restrict__ rec, const __half* __restrict__ hx,
    const float* __restrict__ aS, const float* __restrict__ aD,
    const float* __restrict__ b, float* __restrict__ h1, int n_nodes)
{
    int wv = threadIdx.x >> 6, lane = threadIdx.x & 63;
    int n = blockIdx.x * 4 + wv;
    if (n >= n_nodes) return;
    int start = rowptr[n], end = rowptr[n + 1];
    float aDn = aD[n];
    float r = 0.f, den = 0.f;
    for (int base = start; base < end; base += 64) {
        int cnt = min(end - base, 64);
        int s = 0; float ex = 0.f;
        if (lane < cnt) {
            uint2 R = rec[base + lane];
            s = (int)(R.x & SMASK);
            float s1 = __half2float(__ushort_as_half((unsigned short)(R.y & 0xFFFFu)));
            float a = aS[s] + aDn + s1;
            a = a > 0.f ? a : 0.2f * a;
            ex = __expf(a);
        }
        int j = 0;
        for (; j + 4 <= cnt; j += 4) {
            int s0 = __shfl(s, j), s1i = __shfl(s, j + 1), s2 = __shfl(s, j + 2), s3 = __shfl(s, j + 3);
            float e0 = __shfl(ex, j), e1 = __shfl(ex, j + 1), e2 = __shfl(ex, j + 2), e3 = __shfl(ex, j + 3);
            float h0 = __half2float(hx[(size_t)s0 * 64 + lane]);
            float h1v = __half2float(hx[(size_t)s1i * 64 + lane]);
            float h2 = __half2float(hx[(size_t)s2 * 64 + lane]);
            float h3 = __half2float(hx[(size_t)s3 * 64 + lane]);
            r += e0 * h0; r += e1 * h1v; r += e2 * h2; r += e3 * h3;
            den += e0 + e1 + e2 + e3;
        }
        for (; j < cnt; ++j) {
            int sj = __shfl(s, j); float ej = __shfl(ex, j);
            r += ej * __half2float(hx[(size_t)sj * 64 + lane]);
            den += ej;
        }
    }
    float al = aS[n] + aDn;
    al = al > 0.f ? al : 0.2f * al;
    float exl = __expf(al);
    float hself = __half2float(hx[(size_t)n * 64 + lane]);
    float val = (r + exl * hself) / (den + exl) + b[lane];
    h1[(size_t)n * 64 + lane] = val > 0.f ? val : expm1f(val);
}

// ---- layer-2 node transform: W in regs, h1 via broadcast-b128 LDS reads ----
__global__ __launch_bounds__(256) void k_node2(
    const float* __restrict__ h1, const float* __restrict__ W,
    const float* __restrict__ a_s, const float* __restrict__ a_d,
    float* __restrict__ hx, float* __restrict__ aS, float* __restrict__ aD, int n_nodes)
{
    __shared__ float xs[16][64];
    int tid = threadIdx.x;
    int lane = tid & 63, wv = tid >> 6;
    int half = lane >> 5, c = lane & 31;
    int kb = half << 5;                   // this half accumulates k in [kb, kb+32)
    float wreg[32];
#pragma unroll
    for (int k = 0; k < 32; ++k) wreg[k] = W[(kb + k) * 32 + c];
    float as = a_s[c], ad = a_d[c];
    for (int n0 = blockIdx.x * 16; n0 < n_nodes; n0 += gridDim.x * 16) {
        __syncthreads();
        for (int i = tid; i < 16 * 64; i += 256) {
            int nn = n0 + (i >> 6);
            xs[i >> 6][i & 63] = (nn < n_nodes) ? h1[(size_t)nn * 64 + (i & 63)] : 0.f;
        }
        __syncthreads();
#pragma unroll
        for (int r = 0; r < 4; ++r) {
            int n = n0 + wv * 4 + r;
            if (n >= n_nodes) break;
            const float4* xp = (const float4*)(xs[wv * 4 + r] + kb);
            float h = 0.f;
#pragma unroll
            for (int k4 = 0; k4 < 8; ++k4) {
                float4 xv = xp[k4];       // broadcast within each half
                h += xv.x * wreg[4 * k4] + xv.y * wreg[4 * k4 + 1]
                   + xv.z * wreg[4 * k4 + 2] + xv.w * wreg[4 * k4 + 3];
            }
            h += __shfl_xor(h, 32);       // combine k-halves; both halves now hold h
            float ps = h * as, pd = h * ad;
#pragma unroll
            for (int o = 16; o > 0; o >>= 1) { ps += __shfl_xor(ps, o, 32); pd += __shfl_xor(pd, o, 32); }
            if (half == 0) {
                hx[(size_t)n * 32 + c] = h;
                if (c == 0) { aS[n] = ps; aD[n] = pd; }
            }
        }
    }
}

// ---- layer-2 pull aggregation over masked nodes only + finalize -> out ----
__global__ __launch_bounds__(256) void k_agg2(
    const int* __restrict__ mask, const int* __restrict__ rowptr,
    const uint2* __restrict__ rec, const float* __restrict__ hx,
    const float* __restrict__ aS, const float* __restrict__ aD,
    const float* __restrict__ b, float* __restrict__ out, int m_cnt)
{
    int wv = threadIdx.x >> 6, lane = threadIdx.x & 63;
    int m = blockIdx.x * 4 + wv;
    if (m >= m_cnt) return;
    int n = mask[m];
    int start = rowptr[n], end = rowptr[n + 1];
    float aDn = aD[n];
    int half = lane >> 5, c = lane & 31;
    float r = 0.f, den = 0.f;
    for (int base = start; base < end; base += 64) {
        int cnt = min(end - base, 64);
        int s = 0; float ex = 0.f;
        if (lane < cnt) {
            uint2 R = rec[base + lane];
            s = (int)(R.x & SMASK);
            float ae2 = __half2float(__ushort_as_half((unsigned short)(R.y >> 16)));
            float a = aS[s] + aDn + ae2;
            a = a > 0.f ? a : 0.2f * a;
            ex = __expf(a);
        }
        int j = 0;
        for (; j + 8 <= cnt; j += 8) {
            int j0 = j + half, j2 = j + 2 + half, j4 = j + 4 + half, j6 = j + 6 + half;
            int s0 = __shfl(s, j0), s2v = __shfl(s, j2), s4 = __shfl(s, j4), s6 = __shfl(s, j6);
            float e0 = __shfl(ex, j0), e2 = __shfl(ex, j2), e4 = __shfl(ex, j4), e6 = __shfl(ex, j6);
            r += e0 * hx[(size_t)s0 * 32 + c];
            r += e2 * hx[(size_t)s2v * 32 + c];
            r += e4 * hx[(size_t)s4 * 32 + c];
            r += e6 * hx[(size_t)s6 * 32 + c];
            den += e0 + e2 + e4 + e6;
        }
        for (; j < cnt; j += 2) {
            int jj = j + half;
            if (jj < cnt) {
                int sj = __shfl(s, jj); float ej = __shfl(ex, jj);
                r += ej * hx[(size_t)sj * 32 + c];
                den += ej;
            }
        }
    }
    float ro = __shfl(r, lane ^ 32);
    float do_ = __shfl(den, lane ^ 32);
    r += ro; den += do_;
    if (half == 0) {
        float al = aS[n] + aDn;
        al = al > 0.f ? al : 0.2f * al;
        float exl = __expf(al);
        float val = (r + exl * hx[(size_t)n * 32 + c]) / (den + exl) + b[c];
        out[(size_t)m * 32 + c] = val > 0.f ? val : expm1f(val);
    }
}

extern "C" void kernel_launch(void* const* d_in, const int* in_sizes, int n_in,
                              void* d_out, int out_size, void* d_ws, size_t ws_size,
                              hipStream_t stream) {
    const float* x    = (const float*)d_in[0];
    const int*   ei   = (const int*)d_in[1];
    const int*   mask = (const int*)d_in[2];
    const float* ea   = (const float*)d_in[3];
    const float* W1   = (const float*)d_in[4];
    const float* a_s1 = (const float*)d_in[5];
    const float* a_d1 = (const float*)d_in[6];
    const float* We1  = (const float*)d_in[7];
    const float* a_e1 = (const float*)d_in[8];
    const float* b1   = (const float*)d_in[9];
    const float* W2   = (const float*)d_in[10];
    const float* a_s2 = (const float*)d_in[11];
    const float* a_d2 = (const float*)d_in[12];
    const float* We2  = (const float*)d_in[13];
    const float* a_e2 = (const float*)d_in[14];
    const float* b2   = (const float*)d_in[15];
    const int* src = ei;
    const int* dst = ei + EE;
    float* out = (float*)d_out;

    char* w = (char*)d_ws;
    size_t off = 0;
    auto take = [&](size_t bytes) -> char* {
        char* p = w + off;
        off += (bytes + 255) & ~(size_t)255;
        return p;
    };
    float*    v1      = (float*)take(16 * 4);
    float*    v2      = (float*)take(16 * 4);
    __half*   hx1h    = (__half*)take((size_t)NN * 64 * 2);
    float*    aS1     = (float*)take((size_t)NN * 4);
    float*    aD1     = (float*)take((size_t)NN * 4);
    float*    h1      = (float*)take((size_t)NN * 64 * 4);
    float*    hx2     = (float*)take((size_t)NN * 32 * 4);
    float*    aS2     = (float*)take((size_t)NN * 4);
    float*    aD2     = (float*)take((size_t)NN * 4);
    int*      rowptr  = (int*)take(((size_t)NN + 1) * 4);
    unsigned* ae12    = (unsigned*)take((size_t)EE * 4);
    int*      bh      = (int*)take((size_t)N_SCAN * 4);
    int*      scanned = (int*)take((size_t)N_SCAN * 4);
    int*      bsum    = (int*)take(256 * 4);
    uint2*    recMid  = (uint2*)take((size_t)EE * 8);
    uint2*    rec     = (uint2*)take((size_t)EE * 8);

    const int nb_bh = (N_SCAN + 2047) / 2048;     // 255 (<= 256)

    k_v<<<1, 64, 0, stream>>>(We1, a_e1, We2, a_e2, v1, v2);
    k_node1<<<1024, 256, 0, stream>>>(x, W1, a_s1, a_d1, hx1h, aS1, aD1, NN);
    k_aebh<<<NBLK, 256, 0, stream>>>(ea, v1, v2, dst, ae12, bh, EE);
    k_scan1<<<nb_bh, 256, 0, stream>>>(bh, scanned, bsum, N_SCAN);
    k_scan2<<<1, 256, 0, stream>>>(bsum, nb_bh);
    k_scan3b<<<(N_SCAN + 255) / 256, 256, 0, stream>>>(scanned, bsum, N_SCAN);
    k_part<<<NBLK, 256, 0, stream>>>(src, dst, ae12, scanned, recMid, EE);
    k_build<<<NBC, 256, 0, stream>>>(scanned, recMid, rowptr, rec, EE);
    k_agg1<<<(NN + 3) / 4, 256, 0, stream>>>(rowptr, rec, hx1h, aS1, aD1, b1, h1, NN);
    k_node2<<<1024, 256, 0, stream>>>(h1, W2, a_s2, a_d2, hx2, aS2, aD2, NN);
    k_agg2<<<(MM + 3) / 4, 256, 0, stream>>>(mask, rowptr, rec, hx2, aS2, aD2, b2, out, MM);
}

// Round 15
// 206.112 us; speedup vs baseline: 1.3628x; 1.0211x over previous
//
#include <hip/hip_runtime.h>
#include <hip/hip_bf16.h>
#include <hip/hip_fp16.h>
#include <math.h>

#define NN 100000
#define EE 1600000
#define MM 20000
#define EPB 768                         // edges per partition block (multiple of 256)
#define NBLK ((EE + EPB - 1) / EPB)     // 2084 partition blocks
#define NBC 250                         // coarse dst buckets
#define BWC 400                         // nodes per bucket (250*400 = 100000 exactly)
#define N_SCAN (NBC * NBLK + 1)         // 521001 (+ sentinel)
#define SMASK 0x1FFFF                   // low 17 bits: src id

// ---- tiny: v1[16] = We1 @ a_e1 (64), v2[16] = We2 @ a_e2 (32) ----
__global__ void k_v(const float* __restrict__ We1, const float* __restrict__ ae1v,
                    const float* __restrict__ We2, const float* __restrict__ ae2v,
                    float* __restrict__ v1, float* __restrict__ v2) {
    int t = threadIdx.x;
    if (t < 16) {
        float s = 0.f;
        for (int c = 0; c < 64; ++c) s += We1[t * 64 + c] * ae1v[c];
        v1[t] = s;
    } else if (t < 32) {
        int r = t - 16;
        float s = 0.f;
        for (int c = 0; c < 32; ++c) s += We2[r * 32 + c] * ae2v[c];
        v2[r] = s;
    }
}

// ---- layer-1 node transform: W in regs, x via broadcast-b128 LDS reads ----
__global__ __launch_bounds__(256) void k_node1(
    const float* __restrict__ x, const float* __restrict__ W,
    const float* __restrict__ a_s, const float* __restrict__ a_d,
    __half* __restrict__ hx, float* __restrict__ aS, float* __restrict__ aD,
    int n_nodes)
{
    __shared__ float xs[16][64];
    int tid = threadIdx.x;
    int lane = tid & 63, wv = tid >> 6;
    float wreg[64];
#pragma unroll
    for (int k = 0; k < 64; ++k) wreg[k] = W[k * 64 + lane];
    float as = a_s[lane], ad = a_d[lane];
    for (int n0 = blockIdx.x * 16; n0 < n_nodes; n0 += gridDim.x * 16) {
        __syncthreads();
        for (int i = tid; i < 16 * 64; i += 256) {
            int nn = n0 + (i >> 6);
            xs[i >> 6][i & 63] = (nn < n_nodes) ? x[(size_t)nn * 64 + (i & 63)] : 0.f;
        }
        __syncthreads();
#pragma unroll
        for (int r = 0; r < 4; ++r) {
            int n = n0 + wv * 4 + r;
            if (n >= n_nodes) break;
            const float4* xp = (const float4*)xs[wv * 4 + r];
            float h = 0.f;
#pragma unroll
            for (int k4 = 0; k4 < 16; ++k4) {
                float4 xv = xp[k4];      // broadcast read: all lanes same address
                h += xv.x * wreg[4 * k4] + xv.y * wreg[4 * k4 + 1]
                   + xv.z * wreg[4 * k4 + 2] + xv.w * wreg[4 * k4 + 3];
            }
            hx[(size_t)n * 64 + lane] = __float2half(h);
            float ps = h * as, pd = h * ad;
#pragma unroll
            for (int o = 32; o > 0; o >>= 1) { ps += __shfl_xor(ps, o); pd += __shfl_xor(pd, o); }
            if (lane == 0) { aS[n] = ps; aD[n] = pd; }
        }
    }
}

// ---- fused: edge dots (both layers, fp16-packed) + per-(bucket,block) histogram ----
__global__ __launch_bounds__(256) void k_aebh(
    const float* __restrict__ ea, const float* __restrict__ v1, const float* __restrict__ v2,
    const int* __restrict__ dst, unsigned* __restrict__ ae12,
    int* __restrict__ bh, int E)
{
    __shared__ int hl[NBC];
    int tid = threadIdx.x, blk = blockIdx.x;
    for (int j = tid; j < NBC; j += 256) hl[j] = 0;
    __syncthreads();
    const float4* v14 = (const float4*)v1;
    const float4* v24 = (const float4*)v2;
    float4 va0 = v14[0], va1 = v14[1], va2 = v14[2], va3 = v14[3];
    float4 vb0 = v24[0], vb1 = v24[1], vb2 = v24[2], vb3 = v24[3];
    int e0 = blk * EPB, e1 = min(E, e0 + EPB);
    for (int e = e0 + tid; e < e1; e += 256) {
        const float4* p4 = (const float4*)(ea + (size_t)e * 16);
        float4 q0 = p4[0], q1 = p4[1], q2 = p4[2], q3 = p4[3];
        float s1 = q0.x * va0.x + q0.y * va0.y + q0.z * va0.z + q0.w * va0.w
                 + q1.x * va1.x + q1.y * va1.y + q1.z * va1.z + q1.w * va1.w
                 + q2.x * va2.x + q2.y * va2.y + q2.z * va2.z + q2.w * va2.w
                 + q3.x * va3.x + q3.y * va3.y + q3.z * va3.z + q3.w * va3.w;
        float s2 = q0.x * vb0.x + q0.y * vb0.y + q0.z * vb0.z + q0.w * vb0.w
                 + q1.x * vb1.x + q1.y * vb1.y + q1.z * vb1.z + q1.w * vb1.w
                 + q2.x * vb2.x + q2.y * vb2.y + q2.z * vb2.z + q2.w * vb2.w
                 + q3.x * vb3.x + q3.y * vb3.y + q3.z * vb3.z + q3.w * vb3.w;
        ae12[e] = (unsigned)__half_as_ushort(__float2half(s1))
                | ((unsigned)__half_as_ushort(__float2half(s2)) << 16);
        atomicAdd(&hl[dst[e] / BWC], 1);
    }
    __syncthreads();
    for (int j = tid; j < NBC; j += 256) bh[j * NBLK + blk] = hl[j];
    if (blk == 0 && tid == 0) bh[NBC * NBLK] = 0;   // sentinel -> scan total == E
}

// ---- scan kernels: exclusive prefix (2048 elems/block) ----
__global__ __launch_bounds__(256) void k_scan1(const int* __restrict__ deg, int* __restrict__ pre,
                                               int* __restrict__ bsum, int n) {
    __shared__ int wsum[4];
    int t = threadIdx.x;
    int base = blockIdx.x * 2048 + t * 8;
    int v[8]; int s = 0;
#pragma unroll
    for (int i = 0; i < 8; ++i) { int idx = base + i; int d = (idx < n) ? deg[idx] : 0; v[i] = s; s += d; }
    int lane = t & 63, wv = t >> 6;
    int incl = s;
#pragma unroll
    for (int off = 1; off < 64; off <<= 1) { int y = __shfl_up(incl, off); if (lane >= off) incl += y; }
    if (lane == 63) wsum[wv] = incl;
    __syncthreads();
    int woff = 0;
    for (int w = 0; w < wv; ++w) woff += wsum[w];
    int texcl = woff + incl - s;
#pragma unroll
    for (int i = 0; i < 8; ++i) { int idx = base + i; if (idx < n) pre[idx] = texcl + v[i]; }
    if (t == 255) bsum[blockIdx.x] = woff + incl;
}

__global__ __launch_bounds__(256) void k_scan2(int* __restrict__ bsum, int nb) {
    __shared__ int ws[4];
    int t = threadIdx.x, lane = t & 63, wv = t >> 6;
    int x = (t < nb) ? bsum[t] : 0;
    int incl = x;
#pragma unroll
    for (int off = 1; off < 64; off <<= 1) { int y = __shfl_up(incl, off); if (lane >= off) incl += y; }
    if (lane == 63) ws[wv] = incl;
    __syncthreads();
    int woff = 0;
    for (int w = 0; w < wv; ++w) woff += ws[w];
    if (t < nb) bsum[t] = woff + incl - x;
}

__global__ void k_scan3b(int* __restrict__ pre, const int* __restrict__ bsum, int n) {
    int i = blockIdx.x * 256 + threadIdx.x;
    if (i < n) pre[i] += bsum[i >> 11];
}

// ---- pass 1: pure bookkeeping scatter into 250 coarse dst buckets,
//      block-owned segments, positions from LDS cursors (no global atomics) ----
__global__ __launch_bounds__(256) void k_part(
    const int* __restrict__ src, const int* __restrict__ dst,
    const unsigned* __restrict__ ae12,
    const int* __restrict__ scanned, uint2* __restrict__ recMid, int E)
{
    __shared__ int lcur[NBC];
    int tid = threadIdx.x, blk = blockIdx.x;
    for (int j = tid; j < NBC; j += 256) lcur[j] = scanned[j * NBLK + blk];
    __syncthreads();
    int e0 = blk * EPB, e1 = min(E, e0 + EPB);
    for (int e = e0 + tid; e < e1; e += 256) {
        int s = src[e], d = dst[e];
        unsigned w = ae12[e];
        int b = d / BWC;
        int dloc = d - b * BWC;                       // < 400, 9 bits
        unsigned lo = (unsigned)s | ((unsigned)dloc << 17);
        int pos = atomicAdd(&lcur[b], 1);
        recMid[pos] = make_uint2(lo, w);
    }
}

// ---- pass 2: one block per bucket: LDS hist -> LDS scan -> rowptr -> place ----
__global__ __launch_bounds__(256) void k_build(
    const int* __restrict__ scanned, const uint2* __restrict__ recMid,
    int* __restrict__ rowptr, uint2* __restrict__ rec, int E)
{
    __shared__ int hist[BWC];
    __shared__ int lofs[BWC];
    __shared__ int wsum[4];
    int tid = threadIdx.x, b = blockIdx.x;
    int B0 = scanned[b * NBLK];
    int B1 = scanned[(b + 1) * NBLK];                 // b==NBC-1 hits sentinel == E
    for (int j = tid; j < BWC; j += 256) hist[j] = 0;
    __syncthreads();
    for (int i = B0 + tid; i < B1; i += 256) atomicAdd(&hist[recMid[i].x >> 17], 1);
    __syncthreads();
    // exclusive scan over hist[0..BWC) -> lofs (2 consecutive elems per thread)
    int lane = tid & 63, wv = tid >> 6;
    int i0 = 2 * tid, i1 = 2 * tid + 1;
    int a0 = (i0 < BWC) ? hist[i0] : 0;
    int a1 = (i1 < BWC) ? hist[i1] : 0;
    int s = a0 + a1;
    int incl = s;
#pragma unroll
    for (int off = 1; off < 64; off <<= 1) { int y = __shfl_up(incl, off); if (lane >= off) incl += y; }
    if (lane == 63) wsum[wv] = incl;
    __syncthreads();
    int woff = 0;
    for (int w = 0; w < wv; ++w) woff += wsum[w];
    int base = woff + incl - s;
    if (i0 < BWC) lofs[i0] = base;
    if (i1 < BWC) lofs[i1] = base + a0;
    __syncthreads();
    // rowptr for this bucket (coalesced)
    for (int j = tid; j < BWC; j += 256) rowptr[b * BWC + j] = B0 + lofs[j];
    if (b == NBC - 1 && tid == 0) rowptr[NN] = E;
    __syncthreads();
    // place records at exact CSR slots via LDS cursors
    for (int i = B0 + tid; i < B1; i += 256) {
        uint2 r = recMid[i];
        int nl = (int)(r.x >> 17);
        int p = atomicAdd(&lofs[nl], 1);
        rec[B0 + p] = r;
    }
}

// ---- layer-1 pull aggregation (half2 gathers, 2 cols/lane, 2 edges in flight)
//      + fused finalize (self-loop, div, bias, elu) -> h1 ----
__global__ __launch_bounds__(256) void k_agg1(
    const int* __restrict__ rowptr,
    const uint2* __restrict__ rec, const __half* __restrict__ hx,
    const float* __restrict__ aS, const float* __restrict__ aD,
    const float* __restrict__ b, float* __restrict__ h1, int n_nodes)
{
    int wv = threadIdx.x >> 6, lane = threadIdx.x & 63;
    int n = blockIdx.x * 4 + wv;
    if (n >= n_nodes) return;
    int start = rowptr[n], end = rowptr[n + 1];
    float aDn = aD[n];
    int half = lane >> 5, c = lane & 31;              // lane owns cols 2c, 2c+1
    const __half2* hx2 = (const __half2*)hx;          // row stride: 32 half2
    float rx = 0.f, ry = 0.f, den = 0.f;
    for (int base = start; base < end; base += 64) {
        int cnt = min(end - base, 64);
        int s = 0; float ex = 0.f;
        if (lane < cnt) {
            uint2 R = rec[base + lane];
            s = (int)(R.x & SMASK);
            float s1 = __half2float(__ushort_as_half((unsigned short)(R.y & 0xFFFFu)));
            float a = aS[s] + aDn + s1;
            a = a > 0.f ? a : 0.2f * a;
            ex = __expf(a);
        }
        int j = 0;
        for (; j + 8 <= cnt; j += 8) {
            int j0 = j + half, j2 = j + 2 + half, j4 = j + 4 + half, j6 = j + 6 + half;
            int s0 = __shfl(s, j0), s2v = __shfl(s, j2), s4 = __shfl(s, j4), s6 = __shfl(s, j6);
            float e0 = __shfl(ex, j0), e2 = __shfl(ex, j2), e4 = __shfl(ex, j4), e6 = __shfl(ex, j6);
            float2 h0 = __half22float2(hx2[(size_t)s0 * 32 + c]);
            float2 h2 = __half22float2(hx2[(size_t)s2v * 32 + c]);
            float2 h4 = __half22float2(hx2[(size_t)s4 * 32 + c]);
            float2 h6 = __half22float2(hx2[(size_t)s6 * 32 + c]);
            rx += e0 * h0.x + e2 * h2.x + e4 * h4.x + e6 * h6.x;
            ry += e0 * h0.y + e2 * h2.y + e4 * h4.y + e6 * h6.y;
            den += e0 + e2 + e4 + e6;
        }
        for (; j < cnt; j += 2) {
            int jj = j + half;
            if (jj < cnt) {
                int sj = __shfl(s, jj); float ej = __shfl(ex, jj);
                float2 hj = __half22float2(hx2[(size_t)sj * 32 + c]);
                rx += ej * hj.x; ry += ej * hj.y; den += ej;
            }
        }
    }
    rx += __shfl(rx, lane ^ 32);
    ry += __shfl(ry, lane ^ 32);
    den += __shfl(den, lane ^ 32);
    if (half == 0) {
        float al = aS[n] + aDn;
        al = al > 0.f ? al : 0.2f * al;
        float exl = __expf(al);
        float2 hs = __half22float2(hx2[(size_t)n * 32 + c]);
        float2 bb = ((const float2*)b)[c];
        float inv = 1.f / (den + exl);
        float vx = (rx + exl * hs.x) * inv + bb.x;
        float vy = (ry + exl * hs.y) * inv + bb.y;
        vx = vx > 0.f ? vx : expm1f(vx);
        vy = vy > 0.f ? vy : expm1f(vy);
        ((float2*)h1)[(size_t)n * 32 + c] = make_float2(vx, vy);
    }
}

// ---- layer-2 node transform: W in regs, h1 via broadcast-b128 LDS reads ----
__global__ __launch_bounds__(256) void k_node2(
    const float* __restrict__ h1, const float* __restrict__ W,
    const float* __restrict__ a_s, const float* __restrict__ a_d,
    float* __restrict__ hx, float* __restrict__ aS, float* __restrict__ aD, int n_nodes)
{
    __shared__ float xs[16][64];
    int tid = threadIdx.x;
    int lane = tid & 63, wv = tid >> 6;
    int half = lane >> 5, c = lane & 31;
    int kb = half << 5;                   // this half accumulates k in [kb, kb+32)
    float wreg[32];
#pragma unroll
    for (int k = 0; k < 32; ++k) wreg[k] = W[(kb + k) * 32 + c];
    float as = a_s[c], ad = a_d[c];
    for (int n0 = blockIdx.x * 16; n0 < n_nodes; n0 += gridDim.x * 16) {
        __syncthreads();
        for (int i = tid; i < 16 * 64; i += 256) {
            int nn = n0 + (i >> 6);
            xs[i >> 6][i & 63] = (nn < n_nodes) ? h1[(size_t)nn * 64 + (i & 63)] : 0.f;
        }
        __syncthreads();
#pragma unroll
        for (int r = 0; r < 4; ++r) {
            int n = n0 + wv * 4 + r;
            if (n >= n_nodes) break;
            const float4* xp = (const float4*)(xs[wv * 4 + r] + kb);
            float h = 0.f;
#pragma unroll
            for (int k4 = 0; k4 < 8; ++k4) {
                float4 xv = xp[k4];       // broadcast within each half
                h += xv.x * wreg[4 * k4] + xv.y * wreg[4 * k4 + 1]
                   + xv.z * wreg[4 * k4 + 2] + xv.w * wreg[4 * k4 + 3];
            }
            h += __shfl_xor(h, 32);       // combine k-halves; both halves now hold h
            float ps = h * as, pd = h * ad;
#pragma unroll
            for (int o = 16; o > 0; o >>= 1) { ps += __shfl_xor(ps, o, 32); pd += __shfl_xor(pd, o, 32); }
            if (half == 0) {
                hx[(size_t)n * 32 + c] = h;
                if (c == 0) { aS[n] = ps; aD[n] = pd; }
            }
        }
    }
}

// ---- layer-2 pull aggregation over masked nodes only + finalize -> out ----
__global__ __launch_bounds__(256) void k_agg2(
    const int* __restrict__ mask, const int* __restrict__ rowptr,
    const uint2* __restrict__ rec, const float* __restrict__ hx,
    const float* __restrict__ aS, const float* __restrict__ aD,
    const float* __restrict__ b, float* __restrict__ out, int m_cnt)
{
    int wv = threadIdx.x >> 6, lane = threadIdx.x & 63;
    int m = blockIdx.x * 4 + wv;
    if (m >= m_cnt) return;
    int n = mask[m];
    int start = rowptr[n], end = rowptr[n + 1];
    float aDn = aD[n];
    int half = lane >> 5, c = lane & 31;
    float r = 0.f, den = 0.f;
    for (int base = start; base < end; base += 64) {
        int cnt = min(end - base, 64);
        int s = 0; float ex = 0.f;
        if (lane < cnt) {
            uint2 R = rec[base + lane];
            s = (int)(R.x & SMASK);
            float ae2 = __half2float(__ushort_as_half((unsigned short)(R.y >> 16)));
            float a = aS[s] + aDn + ae2;
            a = a > 0.f ? a : 0.2f * a;
            ex = __expf(a);
        }
        int j = 0;
        for (; j + 8 <= cnt; j += 8) {
            int j0 = j + half, j2 = j + 2 + half, j4 = j + 4 + half, j6 = j + 6 + half;
            int s0 = __shfl(s, j0), s2v = __shfl(s, j2), s4 = __shfl(s, j4), s6 = __shfl(s, j6);
            float e0 = __shfl(ex, j0), e2 = __shfl(ex, j2), e4 = __shfl(ex, j4), e6 = __shfl(ex, j6);
            r += e0 * hx[(size_t)s0 * 32 + c];
            r += e2 * hx[(size_t)s2v * 32 + c];
            r += e4 * hx[(size_t)s4 * 32 + c];
            r += e6 * hx[(size_t)s6 * 32 + c];
            den += e0 + e2 + e4 + e6;
        }
        for (; j < cnt; j += 2) {
            int jj = j + half;
            if (jj < cnt) {
                int sj = __shfl(s, jj); float ej = __shfl(ex, jj);
                r += ej * hx[(size_t)sj * 32 + c];
                den += ej;
            }
        }
    }
    float ro = __shfl(r, lane ^ 32);
    float do_ = __shfl(den, lane ^ 32);
    r += ro; den += do_;
    if (half == 0) {
        float al = aS[n] + aDn;
        al = al > 0.f ? al : 0.2f * al;
        float exl = __expf(al);
        float val = (r + exl * hx[(size_t)n * 32 + c]) / (den + exl) + b[c];
        out[(size_t)m * 32 + c] = val > 0.f ? val : expm1f(val);
    }
}

extern "C" void kernel_launch(void* const* d_in, const int* in_sizes, int n_in,
                              void* d_out, int out_size, void* d_ws, size_t ws_size,
                              hipStream_t stream) {
    const float* x    = (const float*)d_in[0];
    const int*   ei   = (const int*)d_in[1];
    const int*   mask = (const int*)d_in[2];
    const float* ea   = (const float*)d_in[3];
    const float* W1   = (const float*)d_in[4];
    const float* a_s1 = (const float*)d_in[5];
    const float* a_d1 = (const float*)d_in[6];
    const float* We1  = (const float*)d_in[7];
    const float* a_e1 = (const float*)d_in[8];
    const float* b1   = (const float*)d_in[9];
    const float* W2   = (const float*)d_in[10];
    const float* a_s2 = (const float*)d_in[11];
    const float* a_d2 = (const float*)d_in[12];
    const float* We2  = (const float*)d_in[13];
    const float* a_e2 = (const float*)d_in[14];
    const float* b2   = (const float*)d_in[15];
    const int* src = ei;
    const int* dst = ei + EE;
    float* out = (float*)d_out;

    char* w = (char*)d_ws;
    size_t off = 0;
    auto take = [&](size_t bytes) -> char* {
        char* p = w + off;
        off += (bytes + 255) & ~(size_t)255;
        return p;
    };
    float*    v1      = (float*)take(16 * 4);
    float*    v2      = (float*)take(16 * 4);
    __half*   hx1h    = (__half*)take((size_t)NN * 64 * 2);
    float*    aS1     = (float*)take((size_t)NN * 4);
    float*    aD1     = (float*)take((size_t)NN * 4);
    float*    h1      = (float*)take((size_t)NN * 64 * 4);
    float*    hx2     = (float*)take((size_t)NN * 32 * 4);
    float*    aS2     = (float*)take((size_t)NN * 4);
    float*    aD2     = (float*)take((size_t)NN * 4);
    int*      rowptr  = (int*)take(((size_t)NN + 1) * 4);
    unsigned* ae12    = (unsigned*)take((size_t)EE * 4);
    int*      bh      = (int*)take((size_t)N_SCAN * 4);
    int*      scanned = (int*)take((size_t)N_SCAN * 4);
    int*      bsum    = (int*)take(256 * 4);
    uint2*    recMid  = (uint2*)take((size_t)EE * 8);
    uint2*    rec     = (uint2*)take((size_t)EE * 8);

    const int nb_bh = (N_SCAN + 2047) / 2048;     // 255 (<= 256)

    k_v<<<1, 64, 0, stream>>>(We1, a_e1, We2, a_e2, v1, v2);
    k_node1<<<1024, 256, 0, stream>>>(x, W1, a_s1, a_d1, hx1h, aS1, aD1, NN);
    k_aebh<<<NBLK, 256, 0, stream>>>(ea, v1, v2, dst, ae12, bh, EE);
    k_scan1<<<nb_bh, 256, 0, stream>>>(bh, scanned, bsum, N_SCAN);
    k_scan2<<<1, 256, 0, stream>>>(bsum, nb_bh);
    k_scan3b<<<(N_SCAN + 255) / 256, 256, 0, stream>>>(scanned, bsum, N_SCAN);
    k_part<<<NBLK, 256, 0, stream>>>(src, dst, ae12, scanned, recMid, EE);
    k_build<<<NBC, 256, 0, stream>>>(scanned, recMid, rowptr, rec, EE);
    k_agg1<<<(NN + 3) / 4, 256, 0, stream>>>(rowptr, rec, hx1h, aS1, aD1, b1, h1, NN);
    k_node2<<<1024, 256, 0, stream>>>(h1, W2, a_s2, a_d2, hx2, aS2, aD2, NN);
    k_agg2<<<(MM + 3) / 4, 256, 0, stream>>>(mask, rowptr, rec, hx2, aS2, aD2, b2, out, MM);
}

// Round 17
// 205.648 us; speedup vs baseline: 1.3659x; 1.0023x over previous
//
#include <hip/hip_runtime.h>
#include <hip/hip_bf16.h>
#include <hip/hip_fp16.h>
#include <math.h>

#define NN 100000
#define EE 1600000
#define MM 20000
#define EPB 768                         // edges per partition block (multiple of 256)
#define NBLK ((EE + EPB - 1) / EPB)     // 2084 partition blocks
#define NBC 250                         // coarse dst buckets
#define BWC 400                         // nodes per bucket (250*400 = 100000 exactly)
#define N_SCAN (NBC * NBLK + 1)         // 521001 (+ sentinel)
#define SMASK 0x1FFFF                   // low 17 bits: src id

// ---- tiny: v1[16] = We1 @ a_e1 (64), v2[16] = We2 @ a_e2 (32) ----
__global__ void k_v(const float* __restrict__ We1, const float* __restrict__ ae1v,
                    const float* __restrict__ We2, const float* __restrict__ ae2v,
                    float* __restrict__ v1, float* __restrict__ v2) {
    int t = threadIdx.x;
    if (t < 16) {
        float s = 0.f;
        for (int c = 0; c < 64; ++c) s += We1[t * 64 + c] * ae1v[c];
        v1[t] = s;
    } else if (t < 32) {
        int r = t - 16;
        float s = 0.f;
        for (int c = 0; c < 32; ++c) s += We2[r * 32 + c] * ae2v[c];
        v2[r] = s;
    }
}

// ---- layer-1 node transform: W in regs, x via broadcast-b128 LDS reads ----
__global__ __launch_bounds__(256) void k_node1(
    const float* __restrict__ x, const float* __restrict__ W,
    const float* __restrict__ a_s, const float* __restrict__ a_d,
    __half* __restrict__ hx, float* __restrict__ aS, float* __restrict__ aD,
    int n_nodes)
{
    __shared__ float xs[16][64];
    int tid = threadIdx.x;
    int lane = tid & 63, wv = tid >> 6;
    float wreg[64];
#pragma unroll
    for (int k = 0; k < 64; ++k) wreg[k] = W[k * 64 + lane];
    float as = a_s[lane], ad = a_d[lane];
    for (int n0 = blockIdx.x * 16; n0 < n_nodes; n0 += gridDim.x * 16) {
        __syncthreads();
        for (int i = tid; i < 16 * 64; i += 256) {
            int nn = n0 + (i >> 6);
            xs[i >> 6][i & 63] = (nn < n_nodes) ? x[(size_t)nn * 64 + (i & 63)] : 0.f;
        }
        __syncthreads();
#pragma unroll
        for (int r = 0; r < 4; ++r) {
            int n = n0 + wv * 4 + r;
            if (n >= n_nodes) break;
            const float4* xp = (const float4*)xs[wv * 4 + r];
            float h = 0.f;
#pragma unroll
            for (int k4 = 0; k4 < 16; ++k4) {
                float4 xv = xp[k4];      // broadcast read: all lanes same address
                h += xv.x * wreg[4 * k4] + xv.y * wreg[4 * k4 + 1]
                   + xv.z * wreg[4 * k4 + 2] + xv.w * wreg[4 * k4 + 3];
            }
            hx[(size_t)n * 64 + lane] = __float2half(h);
            float ps = h * as, pd = h * ad;
#pragma unroll
            for (int o = 32; o > 0; o >>= 1) { ps += __shfl_xor(ps, o); pd += __shfl_xor(pd, o); }
            if (lane == 0) { aS[n] = ps; aD[n] = pd; }
        }
    }
}

// ---- fused: edge dots (both layers, fp16-packed) + per-(bucket,block) histogram ----
__global__ __launch_bounds__(256) void k_aebh(
    const float* __restrict__ ea, const float* __restrict__ v1, const float* __restrict__ v2,
    const int* __restrict__ dst, unsigned* __restrict__ ae12,
    int* __restrict__ bh, int E)
{
    __shared__ int hl[NBC];
    int tid = threadIdx.x, blk = blockIdx.x;
    for (int j = tid; j < NBC; j += 256) hl[j] = 0;
    __syncthreads();
    const float4* v14 = (const float4*)v1;
    const float4* v24 = (const float4*)v2;
    float4 va0 = v14[0], va1 = v14[1], va2 = v14[2], va3 = v14[3];
    float4 vb0 = v24[0], vb1 = v24[1], vb2 = v24[2], vb3 = v24[3];
    int e0 = blk * EPB, e1 = min(E, e0 + EPB);
    for (int e = e0 + tid; e < e1; e += 256) {
        const float4* p4 = (const float4*)(ea + (size_t)e * 16);
        float4 q0 = p4[0], q1 = p4[1], q2 = p4[2], q3 = p4[3];
        float s1 = q0.x * va0.x + q0.y * va0.y + q0.z * va0.z + q0.w * va0.w
                 + q1.x * va1.x + q1.y * va1.y + q1.z * va1.z + q1.w * va1.w
                 + q2.x * va2.x + q2.y * va2.y + q2.z * va2.z + q2.w * va2.w
                 + q3.x * va3.x + q3.y * va3.y + q3.z * va3.z + q3.w * va3.w;
        float s2 = q0.x * vb0.x + q0.y * vb0.y + q0.z * vb0.z + q0.w * vb0.w
                 + q1.x * vb1.x + q1.y * vb1.y + q1.z * vb1.z + q1.w * vb1.w
                 + q2.x * vb2.x + q2.y * vb2.y + q2.z * vb2.z + q2.w * vb2.w
                 + q3.x * vb3.x + q3.y * vb3.y + q3.z * vb3.z + q3.w * vb3.w;
        ae12[e] = (unsigned)__half_as_ushort(__float2half(s1))
                | ((unsigned)__half_as_ushort(__float2half(s2)) << 16);
        atomicAdd(&hl[dst[e] / BWC], 1);
    }
    __syncthreads();
    for (int j = tid; j < NBC; j += 256) bh[j * NBLK + blk] = hl[j];
    if (blk == 0 && tid == 0) bh[NBC * NBLK] = 0;   // sentinel -> scan total == E
}

// ---- scan kernels: exclusive prefix (2048 elems/block) ----
__global__ __launch_bounds__(256) void k_scan1(const int* __restrict__ deg, int* __restrict__ pre,
                                               int* __restrict__ bsum, int n) {
    __shared__ int wsum[4];
    int t = threadIdx.x;
    int base = blockIdx.x * 2048 + t * 8;
    int v[8]; int s = 0;
#pragma unroll
    for (int i = 0; i < 8; ++i) { int idx = base + i; int d = (idx < n) ? deg[idx] : 0; v[i] = s; s += d; }
    int lane = t & 63, wv = t >> 6;
    int incl = s;
#pragma unroll
    for (int off = 1; off < 64; off <<= 1) { int y = __shfl_up(incl, off); if (lane >= off) incl += y; }
    if (lane == 63) wsum[wv] = incl;
    __syncthreads();
    int woff = 0;
    for (int w = 0; w < wv; ++w) woff += wsum[w];
    int texcl = woff + incl - s;
#pragma unroll
    for (int i = 0; i < 8; ++i) { int idx = base + i; if (idx < n) pre[idx] = texcl + v[i]; }
    if (t == 255) bsum[blockIdx.x] = woff + incl;
}

__global__ __launch_bounds__(256) void k_scan2(int* __restrict__ bsum, int nb) {
    __shared__ int ws[4];
    int t = threadIdx.x, lane = t & 63, wv = t >> 6;
    int x = (t < nb) ? bsum[t] : 0;
    int incl = x;
#pragma unroll
    for (int off = 1; off < 64; off <<= 1) { int y = __shfl_up(incl, off); if (lane >= off) incl += y; }
    if (lane == 63) ws[wv] = incl;
    __syncthreads();
    int woff = 0;
    for (int w = 0; w < wv; ++w) woff += ws[w];
    if (t < nb) bsum[t] = woff + incl - x;
}

__global__ void k_scan3b(int* __restrict__ pre, const int* __restrict__ bsum, int n) {
    int i = blockIdx.x * 256 + threadIdx.x;
    if (i < n) pre[i] += bsum[i >> 11];
}

// ---- pass 1: pure bookkeeping scatter into 250 coarse dst buckets,
//      block-owned segments, positions from LDS cursors (no global atomics) ----
__global__ __launch_bounds__(256) void k_part(
    const int* __restrict__ src, const int* __restrict__ dst,
    const unsigned* __restrict__ ae12,
    const int* __restrict__ scanned, uint2* __restrict__ recMid, int E)
{
    __shared__ int lcur[NBC];
    int tid = threadIdx.x, blk = blockIdx.x;
    for (int j = tid; j < NBC; j += 256) lcur[j] = scanned[j * NBLK + blk];
    __syncthreads();
    int e0 = blk * EPB, e1 = min(E, e0 + EPB);
    for (int e = e0 + tid; e < e1; e += 256) {
        int s = src[e], d = dst[e];
        unsigned w = ae12[e];
        int b = d / BWC;
        int dloc = d - b * BWC;                       // < 400, 9 bits
        unsigned lo = (unsigned)s | ((unsigned)dloc << 17);
        int pos = atomicAdd(&lcur[b], 1);
        recMid[pos] = make_uint2(lo, w);
    }
}

// ---- pass 2: one block per bucket: LDS hist -> LDS scan -> rowptr -> place ----
__global__ __launch_bounds__(256) void k_build(
    const int* __restrict__ scanned, const uint2* __restrict__ recMid,
    int* __restrict__ rowptr, uint2* __restrict__ rec, int E)
{
    __shared__ int hist[BWC];
    __shared__ int lofs[BWC];
    __shared__ int wsum[4];
    int tid = threadIdx.x, b = blockIdx.x;
    int B0 = scanned[b * NBLK];
    int B1 = scanned[(b + 1) * NBLK];                 // b==NBC-1 hits sentinel == E
    for (int j = tid; j < BWC; j += 256) hist[j] = 0;
    __syncthreads();
    for (int i = B0 + tid; i < B1; i += 256) atomicAdd(&hist[recMid[i].x >> 17], 1);
    __syncthreads();
    // exclusive scan over hist[0..BWC) -> lofs (2 consecutive elems per thread)
    int lane = tid & 63, wv = tid >> 6;
    int i0 = 2 * tid, i1 = 2 * tid + 1;
    int a0 = (i0 < BWC) ? hist[i0] : 0;
    int a1 = (i1 < BWC) ? hist[i1] : 0;
    int s = a0 + a1;
    int incl = s;
#pragma unroll
    for (int off = 1; off < 64; off <<= 1) { int y = __shfl_up(incl, off); if (lane >= off) incl += y; }
    if (lane == 63) wsum[wv] = incl;
    __syncthreads();
    int woff = 0;
    for (int w = 0; w < wv; ++w) woff += wsum[w];
    int base = woff + incl - s;
    if (i0 < BWC) lofs[i0] = base;
    if (i1 < BWC) lofs[i1] = base + a0;
    __syncthreads();
    // rowptr for this bucket (coalesced)
    for (int j = tid; j < BWC; j += 256) rowptr[b * BWC + j] = B0 + lofs[j];
    if (b == NBC - 1 && tid == 0) rowptr[NN] = E;
    __syncthreads();
    // place records at exact CSR slots via LDS cursors
    for (int i = B0 + tid; i < B1; i += 256) {
        uint2 r = recMid[i];
        int nl = (int)(r.x >> 17);
        int p = atomicAdd(&lofs[nl], 1);
        rec[B0 + p] = r;
    }
}

// ---- layer-1 pull aggregation (half2 gathers, 2 cols/lane, 2 edges in flight)
//      + fused finalize (self-loop, div, bias, elu) -> h1 ----
__global__ __launch_bounds__(256) void k_agg1(
    const int* __restrict__ rowptr,
    const uint2* __restrict__ rec, const __half* __restrict__ hx,
    const float* __restrict__ aS, const float* __restrict__ aD,
    const float* __restrict__ b, float* __restrict__ h1, int n_nodes)
{
    int wv = threadIdx.x >> 6, lane = threadIdx.x & 63;
    int n = blockIdx.x * 4 + wv;
    if (n >= n_nodes) return;
    int start = rowptr[n], end = rowptr[n + 1];
    float aDn = aD[n];
    int half = lane >> 5, c = lane & 31;              // lane owns cols 2c, 2c+1
    const __half2* hx2 = (const __half2*)hx;          // row stride: 32 half2
    float rx = 0.f, ry = 0.f, den = 0.f;
    for (int base = start; base < end; base += 64) {
        int cnt = min(end - base, 64);
        int s = 0; float ex = 0.f;
        if (lane < cnt) {
            uint2 R = rec[base + lane];
            s = (int)(R.x & SMASK);
            float s1 = __half2float(__ushort_as_half((unsigned short)(R.y & 0xFFFFu)));
            float a = aS[s] + aDn + s1;
            a = a > 0.f ? a : 0.2f * a;
            ex = __expf(a);
        }
        int j = 0;
        for (; j + 8 <= cnt; j += 8) {
            int j0 = j + half, j2 = j + 2 + half, j4 = j + 4 + half, j6 = j + 6 + half;
            int s0 = __shfl(s, j0), s2v = __shfl(s, j2), s4 = __shfl(s, j4), s6 = __shfl(s, j6);
            float e0 = __shfl(ex, j0), e2 = __shfl(ex, j2), e4 = __shfl(ex, j4), e6 = __shfl(ex, j6);
            float2 h0 = __half22float2(hx2[(size_t)s0 * 32 + c]);
            float2 h2 = __half22float2(hx2[(size_t)s2v * 32 + c]);
            float2 h4 = __half22float2(hx2[(size_t)s4 * 32 + c]);
            float2 h6 = __half22float2(hx2[(size_t)s6 * 32 + c]);
            rx += e0 * h0.x + e2 * h2.x + e4 * h4.x + e6 * h6.x;
            ry += e0 * h0.y + e2 * h2.y + e4 * h4.y + e6 * h6.y;
            den += e0 + e2 + e4 + e6;
        }
        for (; j < cnt; j += 2) {
            int jj = j + half;
            if (jj < cnt) {
                int sj = __shfl(s, jj); float ej = __shfl(ex, jj);
                float2 hj = __half22float2(hx2[(size_t)sj * 32 + c]);
                rx += ej * hj.x; ry += ej * hj.y; den += ej;
            }
        }
    }
    rx += __shfl(rx, lane ^ 32);
    ry += __shfl(ry, lane ^ 32);
    den += __shfl(den, lane ^ 32);
    if (half == 0) {
        float al = aS[n] + aDn;
        al = al > 0.f ? al : 0.2f * al;
        float exl = __expf(al);
        float2 hs = __half22float2(hx2[(size_t)n * 32 + c]);
        float2 bb = ((const float2*)b)[c];
        float inv = 1.f / (den + exl);
        float vx = (rx + exl * hs.x) * inv + bb.x;
        float vy = (ry + exl * hs.y) * inv + bb.y;
        vx = vx > 0.f ? vx : expm1f(vx);
        vy = vy > 0.f ? vy : expm1f(vy);
        ((float2*)h1)[(size_t)n * 32 + c] = make_float2(vx, vy);
    }
}

// ---- layer-2 node transform: W in regs, h1 via broadcast-b128 LDS reads ----
__global__ __launch_bounds__(256) void k_node2(
    const float* __restrict__ h1, const float* __restrict__ W,
    const float* __restrict__ a_s, const float* __restrict__ a_d,
    float* __restrict__ hx, float* __restrict__ aS, float* __restrict__ aD, int n_nodes)
{
    __shared__ float xs[16][64];
    int tid = threadIdx.x;
    int lane = tid & 63, wv = tid >> 6;
    int half = lane >> 5, c = lane & 31;
    int kb = half << 5;                   // this half accumulates k in [kb, kb+32)
    float wreg[32];
#pragma unroll
    for (int k = 0; k < 32; ++k) wreg[k] = W[(kb + k) * 32 + c];
    float as = a_s[c], ad = a_d[c];
    for (int n0 = blockIdx.x * 16; n0 < n_nodes; n0 += gridDim.x * 16) {
        __syncthreads();
        for (int i = tid; i < 16 * 64; i += 256) {
            int nn = n0 + (i >> 6);
            xs[i >> 6][i & 63] = (nn < n_nodes) ? h1[(size_t)nn * 64 + (i & 63)] : 0.f;
        }
        __syncthreads();
#pragma unroll
        for (int r = 0; r < 4; ++r) {
            int n = n0 + wv * 4 + r;
            if (n >= n_nodes) break;
            const float4* xp = (const float4*)(xs[wv * 4 + r] + kb);
            float h = 0.f;
#pragma unroll
            for (int k4 = 0; k4 < 8; ++k4) {
                float4 xv = xp[k4];       // broadcast within each half
                h += xv.x * wreg[4 * k4] + xv.y * wreg[4 * k4 + 1]
                   + xv.z * wreg[4 * k4 + 2] + xv.w * wreg[4 * k4 + 3];
            }
            h += __shfl_xor(h, 32);       // combine k-halves; both halves now hold h
            float ps = h * as, pd = h * ad;
#pragma unroll
            for (int o = 16; o > 0; o >>= 1) { ps += __shfl_xor(ps, o, 32); pd += __shfl_xor(pd, o, 32); }
            if (half == 0) {
                hx[(size_t)n * 32 + c] = h;
                if (c == 0) { aS[n] = ps; aD[n] = pd; }
            }
        }
    }
}

// ---- layer-2 pull aggregation over masked nodes only + finalize -> out ----
__global__ __launch_bounds__(256) void k_agg2(
    const int* __restrict__ mask, const int* __restrict__ rowptr,
    const uint2* __restrict__ rec, const float* __restrict__ hx,
    const float* __restrict__ aS, const float* __restrict__ aD,
    const float* __restrict__ b, float* __restrict__ out, int m_cnt)
{
    int wv = threadIdx.x >> 6, lane = threadIdx.x & 63;
    int m = blockIdx.x * 4 + wv;
    if (m >= m_cnt) return;
    int n = mask[m];
    int start = rowptr[n], end = rowptr[n + 1];
    float aDn = aD[n];
    int half = lane >> 5, c = lane & 31;
    float r = 0.f, den = 0.f;
    for (int base = start; base < end; base += 64) {
        int cnt = min(end - base, 64);
        int s = 0; float ex = 0.f;
        if (lane < cnt) {
            uint2 R = rec[base + lane];
            s = (int)(R.x & SMASK);
            float ae2 = __half2float(__ushort_as_half((unsigned short)(R.y >> 16)));
            float a = aS[s] + aDn + ae2;
            a = a > 0.f ? a : 0.2f * a;
            ex = __expf(a);
        }
        int j = 0;
        for (; j + 8 <= cnt; j += 8) {
            int j0 = j + half, j2 = j + 2 + half, j4 = j + 4 + half, j6 = j + 6 + half;
            int s0 = __shfl(s, j0), s2v = __shfl(s, j2), s4 = __shfl(s, j4), s6 = __shfl(s, j6);
            float e0 = __shfl(ex, j0), e2 = __shfl(ex, j2), e4 = __shfl(ex, j4), e6 = __shfl(ex, j6);
            r += e0 * hx[(size_t)s0 * 32 + c];
            r += e2 * hx[(size_t)s2v * 32 + c];
            r += e4 * hx[(size_t)s4 * 32 + c];
            r += e6 * hx[(size_t)s6 * 32 + c];
            den += e0 + e2 + e4 + e6;
        }
        for (; j < cnt; j += 2) {
            int jj = j + half;
            if (jj < cnt) {
                int sj = __shfl(s, jj); float ej = __shfl(ex, jj);
                r += ej * hx[(size_t)sj * 32 + c];
                den += ej;
            }
        }
    }
    float ro = __shfl(r, lane ^ 32);
    float do_ = __shfl(den, lane ^ 32);
    r += ro; den += do_;
    if (half == 0) {
        float al = aS[n] + aDn;
        al = al > 0.f ? al : 0.2f * al;
        float exl = __expf(al);
        float val = (r + exl * hx[(size_t)n * 32 + c]) / (den + exl) + b[c];
        out[(size_t)m * 32 + c] = val > 0.f ? val : expm1f(val);
    }
}

extern "C" void kernel_launch(void* const* d_in, const int* in_sizes, int n_in,
                              void* d_out, int out_size, void* d_ws, size_t ws_size,
                              hipStream_t stream) {
    const float* x    = (const float*)d_in[0];
    const int*   ei   = (const int*)d_in[1];
    const int*   mask = (const int*)d_in[2];
    const float* ea   = (const float*)d_in[3];
    const float* W1   = (const float*)d_in[4];
    const float* a_s1 = (const float*)d_in[5];
    const float* a_d1 = (const float*)d_in[6];
    const float* We1  = (const float*)d_in[7];
    const float* a_e1 = (const float*)d_in[8];
    const float* b1   = (const float*)d_in[9];
    const float* W2   = (const float*)d_in[10];
    const float* a_s2 = (const float*)d_in[11];
    const float* a_d2 = (const float*)d_in[12];
    const float* We2  = (const float*)d_in[13];
    const float* a_e2 = (const float*)d_in[14];
    const float* b2   = (const float*)d_in[15];
    const int* src = ei;
    const int* dst = ei + EE;
    float* out = (float*)d_out;

    char* w = (char*)d_ws;
    size_t off = 0;
    auto take = [&](size_t bytes) -> char* {
        char* p = w + off;
        off += (bytes + 255) & ~(size_t)255;
        return p;
    };
    float*    v1      = (float*)take(16 * 4);
    float*    v2      = (float*)take(16 * 4);
    __half*   hx1h    = (__half*)take((size_t)NN * 64 * 2);
    float*    aS1     = (float*)take((size_t)NN * 4);
    float*    aD1     = (float*)take((size_t)NN * 4);
    float*    h1      = (float*)take((size_t)NN * 64 * 4);
    float*    hx2     = (float*)take((size_t)NN * 32 * 4);
    float*    aS2     = (float*)take((size_t)NN * 4);
    float*    aD2     = (float*)take((size_t)NN * 4);
    int*      rowptr  = (int*)take(((size_t)NN + 1) * 4);
    unsigned* ae12    = (unsigned*)take((size_t)EE * 4);
    int*      bh      = (int*)take((size_t)N_SCAN * 4);
    int*      scanned = (int*)take((size_t)N_SCAN * 4);
    int*      bsum    = (int*)take(256 * 4);
    uint2*    recMid  = (uint2*)take((size_t)EE * 8);
    uint2*    rec     = (uint2*)take((size_t)EE * 8);

    const int nb_bh = (N_SCAN + 2047) / 2048;     // 255 (<= 256)

    k_v<<<1, 64, 0, stream>>>(We1, a_e1, We2, a_e2, v1, v2);
    k_node1<<<1024, 256, 0, stream>>>(x, W1, a_s1, a_d1, hx1h, aS1, aD1, NN);
    k_aebh<<<NBLK, 256, 0, stream>>>(ea, v1, v2, dst, ae12, bh, EE);
    k_scan1<<<nb_bh, 256, 0, stream>>>(bh, scanned, bsum, N_SCAN);
    k_scan2<<<1, 256, 0, stream>>>(bsum, nb_bh);
    k_scan3b<<<(N_SCAN + 255) / 256, 256, 0, stream>>>(scanned, bsum, N_SCAN);
    k_part<<<NBLK, 256, 0, stream>>>(src, dst, ae12, scanned, recMid, EE);
    k_build<<<NBC, 256, 0, stream>>>(scanned, recMid, rowptr, rec, EE);
    k_agg1<<<(NN + 3) / 4, 256, 0, stream>>>(rowptr, rec, hx1h, aS1, aD1, b1, h1, NN);
    k_node2<<<1024, 256, 0, stream>>>(h1, W2, a_s2, a_d2, hx2, aS2, aD2, NN);
    k_agg2<<<(MM + 3) / 4, 256, 0, stream>>>(mask, rowptr, rec, hx2, aS2, aD2, b2, out, MM);
}

// Round 18
// 200.716 us; speedup vs baseline: 1.3994x; 1.0246x over previous
//
#include <hip/hip_runtime.h>
#include <hip/hip_bf16.h>
#include <hip/hip_fp16.h>
#include <math.h>

#define NN 100000
#define EE 1600000
#define MM 20000
#define EPB 768                         // edges per partition block (multiple of 256)
#define NBLK ((EE + EPB - 1) / EPB)     // 2084 partition blocks
#define NBC 250                         // coarse dst buckets
#define BWC 400                         // nodes per bucket (250*400 = 100000 exactly)
#define N_SCAN (NBC * NBLK + 1)         // 521001 (+ sentinel)
#define SMASK 0x1FFFF                   // low 17 bits: src id
#define NB1 1024                        // node1-role blocks inside k_f1

// ---- tiny: v1[16] = We1 @ a_e1 (64), v2[16] = We2 @ a_e2 (32) ----
__global__ void k_v(const float* __restrict__ We1, const float* __restrict__ ae1v,
                    const float* __restrict__ We2, const float* __restrict__ ae2v,
                    float* __restrict__ v1, float* __restrict__ v2) {
    int t = threadIdx.x;
    if (t < 16) {
        float s = 0.f;
        for (int c = 0; c < 64; ++c) s += We1[t * 64 + c] * ae1v[c];
        v1[t] = s;
    } else if (t < 32) {
        int r = t - 16;
        float s = 0.f;
        for (int c = 0; c < 32; ++c) s += We2[r * 32 + c] * ae2v[c];
        v2[r] = s;
    }
}

// ---- fused independent pair: blocks [0,NBLK) = edge dots + histogram;
//      blocks [NBLK,NBLK+NB1) = layer-1 node transform (disjoint in/out) ----
__global__ __launch_bounds__(256) void k_f1(
    const float* __restrict__ ea, const float* __restrict__ v1, const float* __restrict__ v2,
    const int* __restrict__ dst, unsigned* __restrict__ ae12, int* __restrict__ bh,
    const float* __restrict__ x, const float* __restrict__ W,
    const float* __restrict__ a_s, const float* __restrict__ a_d,
    __half* __restrict__ hx, float* __restrict__ aS, float* __restrict__ aD,
    int E, int n_nodes)
{
    __shared__ int hl[NBC];
    __shared__ float xs[16][64];
    int tid = threadIdx.x;
    if (blockIdx.x < NBLK) {
        // ---------------- aebh body (verbatim) ----------------
        int blk = blockIdx.x;
        for (int j = tid; j < NBC; j += 256) hl[j] = 0;
        __syncthreads();
        const float4* v14 = (const float4*)v1;
        const float4* v24 = (const float4*)v2;
        float4 va0 = v14[0], va1 = v14[1], va2 = v14[2], va3 = v14[3];
        float4 vb0 = v24[0], vb1 = v24[1], vb2 = v24[2], vb3 = v24[3];
        int e0 = blk * EPB, e1 = min(E, e0 + EPB);
        for (int e = e0 + tid; e < e1; e += 256) {
            const float4* p4 = (const float4*)(ea + (size_t)e * 16);
            float4 q0 = p4[0], q1 = p4[1], q2 = p4[2], q3 = p4[3];
            float s1 = q0.x * va0.x + q0.y * va0.y + q0.z * va0.z + q0.w * va0.w
                     + q1.x * va1.x + q1.y * va1.y + q1.z * va1.z + q1.w * va1.w
                     + q2.x * va2.x + q2.y * va2.y + q2.z * va2.z + q2.w * va2.w
                     + q3.x * va3.x + q3.y * va3.y + q3.z * va3.z + q3.w * va3.w;
            float s2 = q0.x * vb0.x + q0.y * vb0.y + q0.z * vb0.z + q0.w * vb0.w
                     + q1.x * vb1.x + q1.y * vb1.y + q1.z * vb1.z + q1.w * vb1.w
                     + q2.x * vb2.x + q2.y * vb2.y + q2.z * vb2.z + q2.w * vb2.w
                     + q3.x * vb3.x + q3.y * vb3.y + q3.z * vb3.z + q3.w * vb3.w;
            ae12[e] = (unsigned)__half_as_ushort(__float2half(s1))
                    | ((unsigned)__half_as_ushort(__float2half(s2)) << 16);
            atomicAdd(&hl[dst[e] / BWC], 1);
        }
        __syncthreads();
        for (int j = tid; j < NBC; j += 256) bh[j * NBLK + blk] = hl[j];
        if (blk == 0 && tid == 0) bh[NBC * NBLK] = 0;   // sentinel -> scan total == E
    } else {
        // ---------------- node1 body (verbatim, gridDim -> NB1) ----------------
        int bid = blockIdx.x - NBLK;
        int lane = tid & 63, wv = tid >> 6;
        float wreg[64];
#pragma unroll
        for (int k = 0; k < 64; ++k) wreg[k] = W[k * 64 + lane];
        float as = a_s[lane], ad = a_d[lane];
        for (int n0 = bid * 16; n0 < n_nodes; n0 += NB1 * 16) {
            __syncthreads();
            for (int i = tid; i < 16 * 64; i += 256) {
                int nn = n0 + (i >> 6);
                xs[i >> 6][i & 63] = (nn < n_nodes) ? x[(size_t)nn * 64 + (i & 63)] : 0.f;
            }
            __syncthreads();
#pragma unroll
            for (int r = 0; r < 4; ++r) {
                int n = n0 + wv * 4 + r;
                if (n >= n_nodes) break;
                const float4* xp = (const float4*)xs[wv * 4 + r];
                float h = 0.f;
#pragma unroll
                for (int k4 = 0; k4 < 16; ++k4) {
                    float4 xv = xp[k4];      // broadcast read: all lanes same address
                    h += xv.x * wreg[4 * k4] + xv.y * wreg[4 * k4 + 1]
                       + xv.z * wreg[4 * k4 + 2] + xv.w * wreg[4 * k4 + 3];
                }
                hx[(size_t)n * 64 + lane] = __float2half(h);
                float ps = h * as, pd = h * ad;
#pragma unroll
                for (int o = 32; o > 0; o >>= 1) { ps += __shfl_xor(ps, o); pd += __shfl_xor(pd, o); }
                if (lane == 0) { aS[n] = ps; aD[n] = pd; }
            }
        }
    }
}

// ---- scan kernels: exclusive prefix (2048 elems/block) ----
__global__ __launch_bounds__(256) void k_scan1(const int* __restrict__ deg, int* __restrict__ pre,
                                               int* __restrict__ bsum, int n) {
    __shared__ int wsum[4];
    int t = threadIdx.x;
    int base = blockIdx.x * 2048 + t * 8;
    int v[8]; int s = 0;
#pragma unroll
    for (int i = 0; i < 8; ++i) { int idx = base + i; int d = (idx < n) ? deg[idx] : 0; v[i] = s; s += d; }
    int lane = t & 63, wv = t >> 6;
    int incl = s;
#pragma unroll
    for (int off = 1; off < 64; off <<= 1) { int y = __shfl_up(incl, off); if (lane >= off) incl += y; }
    if (lane == 63) wsum[wv] = incl;
    __syncthreads();
    int woff = 0;
    for (int w = 0; w < wv; ++w) woff += wsum[w];
    int texcl = woff + incl - s;
#pragma unroll
    for (int i = 0; i < 8; ++i) { int idx = base + i; if (idx < n) pre[idx] = texcl + v[i]; }
    if (t == 255) bsum[blockIdx.x] = woff + incl;
}

__global__ __launch_bounds__(256) void k_scan2(int* __restrict__ bsum, int nb) {
    __shared__ int ws[4];
    int t = threadIdx.x, lane = t & 63, wv = t >> 6;
    int x = (t < nb) ? bsum[t] : 0;
    int incl = x;
#pragma unroll
    for (int off = 1; off < 64; off <<= 1) { int y = __shfl_up(incl, off); if (lane >= off) incl += y; }
    if (lane == 63) ws[wv] = incl;
    __syncthreads();
    int woff = 0;
    for (int w = 0; w < wv; ++w) woff += ws[w];
    if (t < nb) bsum[t] = woff + incl - x;
}

__global__ void k_scan3b(int* __restrict__ pre, const int* __restrict__ bsum, int n) {
    int i = blockIdx.x * 256 + threadIdx.x;
    if (i < n) pre[i] += bsum[i >> 11];
}

// ---- pass 1: pure bookkeeping scatter into 250 coarse dst buckets,
//      block-owned segments, positions from LDS cursors (no global atomics) ----
__global__ __launch_bounds__(256) void k_part(
    const int* __restrict__ src, const int* __restrict__ dst,
    const unsigned* __restrict__ ae12,
    const int* __restrict__ scanned, uint2* __restrict__ recMid, int E)
{
    __shared__ int lcur[NBC];
    int tid = threadIdx.x, blk = blockIdx.x;
    for (int j = tid; j < NBC; j += 256) lcur[j] = scanned[j * NBLK + blk];
    __syncthreads();
    int e0 = blk * EPB, e1 = min(E, e0 + EPB);
    for (int e = e0 + tid; e < e1; e += 256) {
        int s = src[e], d = dst[e];
        unsigned w = ae12[e];
        int b = d / BWC;
        int dloc = d - b * BWC;                       // < 400, 9 bits
        unsigned lo = (unsigned)s | ((unsigned)dloc << 17);
        int pos = atomicAdd(&lcur[b], 1);
        recMid[pos] = make_uint2(lo, w);
    }
}

// ---- pass 2: one block per bucket: LDS hist -> LDS scan -> rowptr -> place ----
__global__ __launch_bounds__(256) void k_build(
    const int* __restrict__ scanned, const uint2* __restrict__ recMid,
    int* __restrict__ rowptr, uint2* __restrict__ rec, int E)
{
    __shared__ int hist[BWC];
    __shared__ int lofs[BWC];
    __shared__ int wsum[4];
    int tid = threadIdx.x, b = blockIdx.x;
    int B0 = scanned[b * NBLK];
    int B1 = scanned[(b + 1) * NBLK];                 // b==NBC-1 hits sentinel == E
    for (int j = tid; j < BWC; j += 256) hist[j] = 0;
    __syncthreads();
    for (int i = B0 + tid; i < B1; i += 256) atomicAdd(&hist[recMid[i].x >> 17], 1);
    __syncthreads();
    // exclusive scan over hist[0..BWC) -> lofs (2 consecutive elems per thread)
    int lane = tid & 63, wv = tid >> 6;
    int i0 = 2 * tid, i1 = 2 * tid + 1;
    int a0 = (i0 < BWC) ? hist[i0] : 0;
    int a1 = (i1 < BWC) ? hist[i1] : 0;
    int s = a0 + a1;
    int incl = s;
#pragma unroll
    for (int off = 1; off < 64; off <<= 1) { int y = __shfl_up(incl, off); if (lane >= off) incl += y; }
    if (lane == 63) wsum[wv] = incl;
    __syncthreads();
    int woff = 0;
    for (int w = 0; w < wv; ++w) woff += wsum[w];
    int base = woff + incl - s;
    if (i0 < BWC) lofs[i0] = base;
    if (i1 < BWC) lofs[i1] = base + a0;
    __syncthreads();
    // rowptr for this bucket (coalesced)
    for (int j = tid; j < BWC; j += 256) rowptr[b * BWC + j] = B0 + lofs[j];
    if (b == NBC - 1 && tid == 0) rowptr[NN] = E;
    __syncthreads();
    // place records at exact CSR slots via LDS cursors
    for (int i = B0 + tid; i < B1; i += 256) {
        uint2 r = recMid[i];
        int nl = (int)(r.x >> 17);
        int p = atomicAdd(&lofs[nl], 1);
        rec[B0 + p] = r;
    }
}

// ---- layer-1 pull aggregation (half2 gathers, 2 cols/lane, 2 edges in flight)
//      + fused finalize (self-loop, div, bias, elu) -> h1 ----
__global__ __launch_bounds__(256) void k_agg1(
    const int* __restrict__ rowptr,
    const uint2* __restrict__ rec, const __half* __restrict__ hx,
    const float* __restrict__ aS, const float* __restrict__ aD,
    const float* __restrict__ b, float* __restrict__ h1, int n_nodes)
{
    int wv = threadIdx.x >> 6, lane = threadIdx.x & 63;
    int n = blockIdx.x * 4 + wv;
    if (n >= n_nodes) return;
    int start = rowptr[n], end = rowptr[n + 1];
    float aDn = aD[n];
    int half = lane >> 5, c = lane & 31;              // lane owns cols 2c, 2c+1
    const __half2* hx2 = (const __half2*)hx;          // row stride: 32 half2
    float rx = 0.f, ry = 0.f, den = 0.f;
    for (int base = start; base < end; base += 64) {
        int cnt = min(end - base, 64);
        int s = 0; float ex = 0.f;
        if (lane < cnt) {
            uint2 R = rec[base + lane];
            s = (int)(R.x & SMASK);
            float s1 = __half2float(__ushort_as_half((unsigned short)(R.y & 0xFFFFu)));
            float a = aS[s] + aDn + s1;
            a = a > 0.f ? a : 0.2f * a;
            ex = __expf(a);
        }
        int j = 0;
        for (; j + 8 <= cnt; j += 8) {
            int j0 = j + half, j2 = j + 2 + half, j4 = j + 4 + half, j6 = j + 6 + half;
            int s0 = __shfl(s, j0), s2v = __shfl(s, j2), s4 = __shfl(s, j4), s6 = __shfl(s, j6);
            float e0 = __shfl(ex, j0), e2 = __shfl(ex, j2), e4 = __shfl(ex, j4), e6 = __shfl(ex, j6);
            float2 h0 = __half22float2(hx2[(size_t)s0 * 32 + c]);
            float2 h2 = __half22float2(hx2[(size_t)s2v * 32 + c]);
            float2 h4 = __half22float2(hx2[(size_t)s4 * 32 + c]);
            float2 h6 = __half22float2(hx2[(size_t)s6 * 32 + c]);
            rx += e0 * h0.x + e2 * h2.x + e4 * h4.x + e6 * h6.x;
            ry += e0 * h0.y + e2 * h2.y + e4 * h4.y + e6 * h6.y;
            den += e0 + e2 + e4 + e6;
        }
        for (; j < cnt; j += 2) {
            int jj = j + half;
            if (jj < cnt) {
                int sj = __shfl(s, jj); float ej = __shfl(ex, jj);
                float2 hj = __half22float2(hx2[(size_t)sj * 32 + c]);
                rx += ej * hj.x; ry += ej * hj.y; den += ej;
            }
        }
    }
    rx += __shfl(rx, lane ^ 32);
    ry += __shfl(ry, lane ^ 32);
    den += __shfl(den, lane ^ 32);
    if (half == 0) {
        float al = aS[n] + aDn;
        al = al > 0.f ? al : 0.2f * al;
        float exl = __expf(al);
        float2 hs = __half22float2(hx2[(size_t)n * 32 + c]);
        float2 bb = ((const float2*)b)[c];
        float inv = 1.f / (den + exl);
        float vx = (rx + exl * hs.x) * inv + bb.x;
        float vy = (ry + exl * hs.y) * inv + bb.y;
        vx = vx > 0.f ? vx : expm1f(vx);
        vy = vy > 0.f ? vy : expm1f(vy);
        ((float2*)h1)[(size_t)n * 32 + c] = make_float2(vx, vy);
    }
}

// ---- layer-2 node transform: W in regs, h1 via broadcast-b128 LDS reads ----
__global__ __launch_bounds__(256) void k_node2(
    const float* __restrict__ h1, const float* __restrict__ W,
    const float* __restrict__ a_s, const float* __restrict__ a_d,
    float* __restrict__ hx, float* __restrict__ aS, float* __restrict__ aD, int n_nodes)
{
    __shared__ float xs[16][64];
    int tid = threadIdx.x;
    int lane = tid & 63, wv = tid >> 6;
    int half = lane >> 5, c = lane & 31;
    int kb = half << 5;                   // this half accumulates k in [kb, kb+32)
    float wreg[32];
#pragma unroll
    for (int k = 0; k < 32; ++k) wreg[k] = W[(kb + k) * 32 + c];
    float as = a_s[c], ad = a_d[c];
    for (int n0 = blockIdx.x * 16; n0 < n_nodes; n0 += gridDim.x * 16) {
        __syncthreads();
        for (int i = tid; i < 16 * 64; i += 256) {
            int nn = n0 + (i >> 6);
            xs[i >> 6][i & 63] = (nn < n_nodes) ? h1[(size_t)nn * 64 + (i & 63)] : 0.f;
        }
        __syncthreads();
#pragma unroll
        for (int r = 0; r < 4; ++r) {
            int n = n0 + wv * 4 + r;
            if (n >= n_nodes) break;
            const float4* xp = (const float4*)(xs[wv * 4 + r] + kb);
            float h = 0.f;
#pragma unroll
            for (int k4 = 0; k4 < 8; ++k4) {
                float4 xv = xp[k4];       // broadcast within each half
                h += xv.x * wreg[4 * k4] + xv.y * wreg[4 * k4 + 1]
                   + xv.z * wreg[4 * k4 + 2] + xv.w * wreg[4 * k4 + 3];
            }
            h += __shfl_xor(h, 32);       // combine k-halves; both halves now hold h
            float ps = h * as, pd = h * ad;
#pragma unroll
            for (int o = 16; o > 0; o >>= 1) { ps += __shfl_xor(ps, o, 32); pd += __shfl_xor(pd, o, 32); }
            if (half == 0) {
                hx[(size_t)n * 32 + c] = h;
                if (c == 0) { aS[n] = ps; aD[n] = pd; }
            }
        }
    }
}

// ---- layer-2 pull aggregation over masked nodes only + finalize -> out ----
__global__ __launch_bounds__(256) void k_agg2(
    const int* __restrict__ mask, const int* __restrict__ rowptr,
    const uint2* __restrict__ rec, const float* __restrict__ hx,
    const float* __restrict__ aS, const float* __restrict__ aD,
    const float* __restrict__ b, float* __restrict__ out, int m_cnt)
{
    int wv = threadIdx.x >> 6, lane = threadIdx.x & 63;
    int m = blockIdx.x * 4 + wv;
    if (m >= m_cnt) return;
    int n = mask[m];
    int start = rowptr[n], end = rowptr[n + 1];
    float aDn = aD[n];
    int half = lane >> 5, c = lane & 31;
    float r = 0.f, den = 0.f;
    for (int base = start; base < end; base += 64) {
        int cnt = min(end - base, 64);
        int s = 0; float ex = 0.f;
        if (lane < cnt) {
            uint2 R = rec[base + lane];
            s = (int)(R.x & SMASK);
            float ae2 = __half2float(__ushort_as_half((unsigned short)(R.y >> 16)));
            float a = aS[s] + aDn + ae2;
            a = a > 0.f ? a : 0.2f * a;
            ex = __expf(a);
        }
        int j = 0;
        for (; j + 8 <= cnt; j += 8) {
            int j0 = j + half, j2 = j + 2 + half, j4 = j + 4 + half, j6 = j + 6 + half;
            int s0 = __shfl(s, j0), s2v = __shfl(s, j2), s4 = __shfl(s, j4), s6 = __shfl(s, j6);
            float e0 = __shfl(ex, j0), e2 = __shfl(ex, j2), e4 = __shfl(ex, j4), e6 = __shfl(ex, j6);
            r += e0 * hx[(size_t)s0 * 32 + c];
            r += e2 * hx[(size_t)s2v * 32 + c];
            r += e4 * hx[(size_t)s4 * 32 + c];
            r += e6 * hx[(size_t)s6 * 32 + c];
            den += e0 + e2 + e4 + e6;
        }
        for (; j < cnt; j += 2) {
            int jj = j + half;
            if (jj < cnt) {
                int sj = __shfl(s, jj); float ej = __shfl(ex, jj);
                r += ej * hx[(size_t)sj * 32 + c];
                den += ej;
            }
        }
    }
    float ro = __shfl(r, lane ^ 32);
    float do_ = __shfl(den, lane ^ 32);
    r += ro; den += do_;
    if (half == 0) {
        float al = aS[n] + aDn;
        al = al > 0.f ? al : 0.2f * al;
        float exl = __expf(al);
        float val = (r + exl * hx[(size_t)n * 32 + c]) / (den + exl) + b[c];
        out[(size_t)m * 32 + c] = val > 0.f ? val : expm1f(val);
    }
}

extern "C" void kernel_launch(void* const* d_in, const int* in_sizes, int n_in,
                              void* d_out, int out_size, void* d_ws, size_t ws_size,
                              hipStream_t stream) {
    const float* x    = (const float*)d_in[0];
    const int*   ei   = (const int*)d_in[1];
    const int*   mask = (const int*)d_in[2];
    const float* ea   = (const float*)d_in[3];
    const float* W1   = (const float*)d_in[4];
    const float* a_s1 = (const float*)d_in[5];
    const float* a_d1 = (const float*)d_in[6];
    const float* We1  = (const float*)d_in[7];
    const float* a_e1 = (const float*)d_in[8];
    const float* b1   = (const float*)d_in[9];
    const float* W2   = (const float*)d_in[10];
    const float* a_s2 = (const float*)d_in[11];
    const float* a_d2 = (const float*)d_in[12];
    const float* We2  = (const float*)d_in[13];
    const float* a_e2 = (const float*)d_in[14];
    const float* b2   = (const float*)d_in[15];
    const int* src = ei;
    const int* dst = ei + EE;
    float* out = (float*)d_out;

    char* w = (char*)d_ws;
    size_t off = 0;
    auto take = [&](size_t bytes) -> char* {
        char* p = w + off;
        off += (bytes + 255) & ~(size_t)255;
        return p;
    };
    float*    v1      = (float*)take(16 * 4);
    float*    v2      = (float*)take(16 * 4);
    __half*   hx1h    = (__half*)take((size_t)NN * 64 * 2);
    float*    aS1     = (float*)take((size_t)NN * 4);
    float*    aD1     = (float*)take((size_t)NN * 4);
    float*    h1      = (float*)take((size_t)NN * 64 * 4);
    float*    hx2     = (float*)take((size_t)NN * 32 * 4);
    float*    aS2     = (float*)take((size_t)NN * 4);
    float*    aD2     = (float*)take((size_t)NN * 4);
    int*      rowptr  = (int*)take(((size_t)NN + 1) * 4);
    unsigned* ae12    = (unsigned*)take((size_t)EE * 4);
    int*      bh      = (int*)take((size_t)N_SCAN * 4);
    int*      scanned = (int*)take((size_t)N_SCAN * 4);
    int*      bsum    = (int*)take(256 * 4);
    uint2*    recMid  = (uint2*)take((size_t)EE * 8);
    uint2*    rec     = (uint2*)take((size_t)EE * 8);

    const int nb_bh = (N_SCAN + 2047) / 2048;     // 255 (<= 256)

    k_v<<<1, 64, 0, stream>>>(We1, a_e1, We2, a_e2, v1, v2);
    k_f1<<<NBLK + NB1, 256, 0, stream>>>(ea, v1, v2, dst, ae12, bh,
                                         x, W1, a_s1, a_d1, hx1h, aS1, aD1, EE, NN);
    k_scan1<<<nb_bh, 256, 0, stream>>>(bh, scanned, bsum, N_SCAN);
    k_scan2<<<1, 256, 0, stream>>>(bsum, nb_bh);
    k_scan3b<<<(N_SCAN + 255) / 256, 256, 0, stream>>>(scanned, bsum, N_SCAN);
    k_part<<<NBLK, 256, 0, stream>>>(src, dst, ae12, scanned, recMid, EE);
    k_build<<<NBC, 256, 0, stream>>>(scanned, recMid, rowptr, rec, EE);
    k_agg1<<<(NN + 3) / 4, 256, 0, stream>>>(rowptr, rec, hx1h, aS1, aD1, b1, h1, NN);
    k_node2<<<1024, 256, 0, stream>>>(h1, W2, a_s2, a_d2, hx2, aS2, aD2, NN);
    k_agg2<<<(MM + 3) / 4, 256, 0, stream>>>(mask, rowptr, rec, hx2, aS2, aD2, b2, out, MM);
}